// Round 7
// baseline (894.181 us; speedup 1.0000x reference)
//
#include <hip/hip_runtime.h>
#include <stdint.h>

typedef unsigned short u16;
typedef unsigned int u32;

#define NSUB 32768
#define NNZ_E 1048576

using short8 = __attribute__((ext_vector_type(8))) short;
using f32x4  = __attribute__((ext_vector_type(4))) float;

__device__ __forceinline__ u16 f2b(float f) {
  u32 u = __float_as_uint(f);
  return (u16)((u + 0x7fffu + ((u >> 16) & 1u)) >> 16);
}
__device__ __forceinline__ float b2f(u16 x) {
  return __uint_as_float(((u32)x) << 16);
}

__device__ __forceinline__ void glds16(const void* g, void* l) {
  __builtin_amdgcn_global_load_lds(
      (const __attribute__((address_space(1))) u32*)g,
      (__attribute__((address_space(3))) u32*)l, 16, 0, 0);
}

// ---------------- weight f32 -> bf16 ----------------
__global__ __launch_bounds__(256) void cvt_bf16(const float* __restrict__ in,
                                                u16* __restrict__ out, int n4) {
  int i = blockIdx.x * 256 + threadIdx.x;
  if (i < n4) {
    float4 v = ((const float4*)in)[i];
    ushort4 o;
    o.x = f2b(v.x); o.y = f2b(v.y); o.z = f2b(v.z); o.w = f2b(v.w);
    ((ushort4*)out)[i] = o;
  }
}

// ---------------- gather + cast ----------------
__global__ __launch_bounds__(128) void gather_cast(const float* __restrict__ ff,
                                                   const int* __restrict__ idx,
                                                   u16* __restrict__ out) {
  int r = blockIdx.x, t = threadIdx.x;
  size_t src = (size_t)idx[r];
  float4 v = *(const float4*)(ff + src * 512 + t * 4);
  ushort4 o;
  o.x = f2b(v.x); o.y = f2b(v.y); o.z = f2b(v.z); o.w = f2b(v.w);
  *(ushort4*)(out + (size_t)r * 512 + t * 4) = o;
}

// ---------------- CSR build, bucketed by column range ----------------
// bucket = col >> 12 (8 buckets of 4096 rows = 4 MiB bf16 rows = one XCD L2).
// Edges land (row, bucket)-sorted so concurrent waves sweep columns in sync.
__global__ __launch_bounds__(256) void edge_count8(const int* __restrict__ row,
                                                   const int* __restrict__ col,
                                                   int* __restrict__ cnt8) {
  int i = blockIdx.x * 256 + threadIdx.x;
  atomicAdd(&cnt8[row[i] * 8 + (col[i] >> 12)], 1);
}

__global__ __launch_bounds__(1024) void scan_rows8(const int* __restrict__ cnt8,
                                                   int* __restrict__ off,
                                                   int* __restrict__ cursor8) {
  __shared__ int part[1024];
  int t = threadIdx.x;
  int base = t * 256;  // 256 counters per thread (= 32 rows)
  int sum = 0;
  for (int j = 0; j < 256; ++j) sum += cnt8[base + j];
  part[t] = sum;
  __syncthreads();
  for (int d = 1; d < 1024; d <<= 1) {
    int v = part[t];
    int u = (t >= d) ? part[t - d] : 0;
    __syncthreads();
    part[t] = v + u;
    __syncthreads();
  }
  int run = part[t] - sum;  // exclusive prefix
  for (int j = 0; j < 256; ++j) {
    int idx = base + j;
    int c = cnt8[idx];
    cursor8[idx] = run;
    if ((idx & 7) == 0) off[idx >> 3] = run;
    run += c;
  }
  if (t == 1023) off[NSUB] = run;  // == NNZ
}

__global__ __launch_bounds__(256) void edge_scatter8(const int* __restrict__ row,
                                                     const int* __restrict__ col,
                                                     const float* __restrict__ val,
                                                     int* __restrict__ cursor8,
                                                     int2* __restrict__ cv) {
  int i = blockIdx.x * 256 + threadIdx.x;
  int c = col[i];
  int p = atomicAdd(&cursor8[row[i] * 8 + (c >> 12)], 1);
  int2 e; e.x = c; e.y = __float_as_int(val[i]);
  cv[p] = e;
}

// ---------------- SpMM, one wave per row, 16B gathers, MLP=4 ----------------
__device__ __forceinline__ void fma8(int4 u, float v, float* a) {
  u32 w;
  w = (u32)u.x; a[0] += v * __uint_as_float(w << 16); a[1] += v * __uint_as_float(w & 0xffff0000u);
  w = (u32)u.y; a[2] += v * __uint_as_float(w << 16); a[3] += v * __uint_as_float(w & 0xffff0000u);
  w = (u32)u.z; a[4] += v * __uint_as_float(w << 16); a[5] += v * __uint_as_float(w & 0xffff0000u);
  w = (u32)u.w; a[6] += v * __uint_as_float(w << 16); a[7] += v * __uint_as_float(w & 0xffff0000u);
}

// NORM=false: plain aggregated features -> bf16
// NORM=true : fused bias+relu+mean/var-norm -> bf16
template <int LDX, bool NORM>
__global__ __launch_bounds__(256) void spmm512(const int* __restrict__ off,
                                               const int2* __restrict__ cv,
                                               const u16* __restrict__ X,
                                               u16* __restrict__ Y, int ldy,
                                               const float* __restrict__ bias,
                                               const float* __restrict__ sc,
                                               const float* __restrict__ ofs) {
  const int lane = threadIdx.x & 63, wave = threadIdx.x >> 6;
  const int r = blockIdx.x * 4 + wave;
  const int s = __builtin_amdgcn_readfirstlane(off[r]);
  const int e = __builtin_amdgcn_readfirstlane(off[r + 1]);
  float a[8] = {0.f, 0.f, 0.f, 0.f, 0.f, 0.f, 0.f, 0.f};
  const u16* Xl = X + lane * 8;
  int i = s;
  for (; i + 4 <= e; i += 4) {
    int2 p0 = cv[i], p1 = cv[i + 1], p2 = cv[i + 2], p3 = cv[i + 3];
    int4 u0 = *(const int4*)(Xl + (size_t)p0.x * LDX);
    int4 u1 = *(const int4*)(Xl + (size_t)p1.x * LDX);
    int4 u2 = *(const int4*)(Xl + (size_t)p2.x * LDX);
    int4 u3 = *(const int4*)(Xl + (size_t)p3.x * LDX);
    fma8(u0, __int_as_float(p0.y), a);
    fma8(u1, __int_as_float(p1.y), a);
    fma8(u2, __int_as_float(p2.y), a);
    fma8(u3, __int_as_float(p3.y), a);
  }
  for (; i < e; ++i) {
    int2 p0 = cv[i];
    int4 u0 = *(const int4*)(Xl + (size_t)p0.x * LDX);
    fma8(u0, __int_as_float(p0.y), a);
  }
  if (NORM) {
    float4 b0 = *(const float4*)(bias + lane * 8);
    float4 b1 = *(const float4*)(bias + lane * 8 + 4);
    a[0] = fmaxf(a[0] + b0.x, 0.f); a[1] = fmaxf(a[1] + b0.y, 0.f);
    a[2] = fmaxf(a[2] + b0.z, 0.f); a[3] = fmaxf(a[3] + b0.w, 0.f);
    a[4] = fmaxf(a[4] + b1.x, 0.f); a[5] = fmaxf(a[5] + b1.y, 0.f);
    a[6] = fmaxf(a[6] + b1.z, 0.f); a[7] = fmaxf(a[7] + b1.w, 0.f);
    float sum = 0.f, sq = 0.f;
#pragma unroll
    for (int j = 0; j < 8; ++j) { sum += a[j]; sq += a[j] * a[j]; }
#pragma unroll
    for (int d = 1; d < 64; d <<= 1) {
      sum += __shfl_xor(sum, d);
      sq  += __shfl_xor(sq, d);
    }
    float mean = sum * (1.f / 512.f);
    float var = sq * (1.f / 512.f) - mean * mean;
    float rstd = rsqrtf(var + 1e-9f);
    float4 s0 = *(const float4*)(sc + lane * 8);
    float4 s1 = *(const float4*)(sc + lane * 8 + 4);
    float4 o0 = *(const float4*)(ofs + lane * 8);
    float4 o1 = *(const float4*)(ofs + lane * 8 + 4);
    int4 o;
    o.x = (int)((u32)f2b((a[0] - mean) * s0.x * rstd + o0.x) |
                ((u32)f2b((a[1] - mean) * s0.y * rstd + o0.y) << 16));
    o.y = (int)((u32)f2b((a[2] - mean) * s0.z * rstd + o0.z) |
                ((u32)f2b((a[3] - mean) * s0.w * rstd + o0.w) << 16));
    o.z = (int)((u32)f2b((a[4] - mean) * s1.x * rstd + o1.x) |
                ((u32)f2b((a[5] - mean) * s1.y * rstd + o1.y) << 16));
    o.w = (int)((u32)f2b((a[6] - mean) * s1.z * rstd + o1.z) |
                ((u32)f2b((a[7] - mean) * s1.w * rstd + o1.w) << 16));
    *(int4*)(Y + (size_t)r * ldy + lane * 8) = o;
  } else {
    int4 o;
    o.x = (int)((u32)f2b(a[0]) | ((u32)f2b(a[1]) << 16));
    o.y = (int)((u32)f2b(a[2]) | ((u32)f2b(a[3]) << 16));
    o.z = (int)((u32)f2b(a[4]) | ((u32)f2b(a[5]) << 16));
    o.w = (int)((u32)f2b(a[6]) | ((u32)f2b(a[7]) << 16));
    *(int4*)(Y + (size_t)r * ldy + lane * 8) = o;
  }
}

// ---------------- bf16 MFMA GEMM: C[M,N] = A[M,K] @ W[N,K]^T ----------------
// 128x128 tile, glds staging, XCD swizzle. RS: scale acc by rs[row] (L2-norm fold).
template <int K, int LDC, bool BIAS, bool BF16OUT, bool RS>
__global__ __launch_bounds__(256) void gemm_bt(const u16* __restrict__ A,
                                               const u16* __restrict__ W,
                                               const float* __restrict__ bias,
                                               const float* __restrict__ rs,
                                               float* __restrict__ Cf,
                                               u16* __restrict__ Cb) {
  __shared__ __align__(16) u16 As[128 * 32];
  __shared__ __align__(16) u16 Bs[128 * 32];
  const int t = threadIdx.x;
  const int lane = t & 63, wave = t >> 6;
  const int wm = (wave >> 1) * 64, wn = (wave & 1) * 64;
  const int nwg = gridDim.x * gridDim.y;
  const int bid = blockIdx.x + gridDim.x * blockIdx.y;
  const int sbid = (bid % 8) * (nwg / 8) + bid / 8;
  const int bx = sbid % gridDim.x, by = sbid / gridDim.x;
  const int m0 = by * 128, n0 = bx * 128;

  f32x4 acc[4][4];
#pragma unroll
  for (int m = 0; m < 4; ++m)
#pragma unroll
    for (int n = 0; n < 4; ++n) acc[m][n] = f32x4{0.f, 0.f, 0.f, 0.f};

  const int lr = t >> 2;
  const int lc = (t & 3) * 8;
  const u16* Ag  = A + (size_t)(m0 + lr) * K + lc;
  const u16* Ag2 = Ag + (size_t)64 * K;
  const u16* Wg  = W + (size_t)(n0 + lr) * K + lc;
  const u16* Wg2 = Wg + (size_t)64 * K;
  char* asb0 = (char*)As + wave * 1024;
  char* asb1 = (char*)As + 4096 + wave * 1024;
  char* bsb0 = (char*)Bs + wave * 1024;
  char* bsb1 = (char*)Bs + 4096 + wave * 1024;
  const int fr = lane & 15, kh = lane >> 4;

  for (int kt = 0; kt < K / 32; ++kt) {
    glds16(Ag + kt * 32, asb0);
    glds16(Ag2 + kt * 32, asb1);
    glds16(Wg + kt * 32, bsb0);
    glds16(Wg2 + kt * 32, bsb1);
    __syncthreads();
    short8 af[4], bfr[4];
#pragma unroll
    for (int m = 0; m < 4; ++m)
      af[m] = *(const short8*)&As[(wm + m * 16 + fr) * 32 + kh * 8];
#pragma unroll
    for (int n = 0; n < 4; ++n)
      bfr[n] = *(const short8*)&Bs[(wn + n * 16 + fr) * 32 + kh * 8];
#pragma unroll
    for (int m = 0; m < 4; ++m)
#pragma unroll
      for (int n = 0; n < 4; ++n)
        acc[m][n] = __builtin_amdgcn_mfma_f32_16x16x32_bf16(af[m], bfr[n], acc[m][n], 0, 0, 0);
    __syncthreads();
  }

  const int crow = (lane >> 4) * 4;
  const int ccol = lane & 15;
#pragma unroll
  for (int n = 0; n < 4; ++n) {
    int col = n0 + wn + n * 16 + ccol;
    float bv = BIAS ? bias[col] : 0.f;
#pragma unroll
    for (int m = 0; m < 4; ++m) {
      int row = m0 + wm + m * 16 + crow;
#pragma unroll
      for (int q = 0; q < 4; ++q) {
        float v = acc[m][n][q];
        if (RS) v *= rs[row + q];
        v += bv;
        if (BF16OUT)
          Cb[(size_t)(row + q) * LDC + col] = f2b(v);
        else
          Cf[(size_t)(row + q) * LDC + col] = v;
      }
    }
  }
}

// ---------------- fused bias + relu + per-row mean/var norm (bf16 in) ----------------
__global__ __launch_bounds__(128) void rownorm_b(const u16* __restrict__ F, int ldf,
                                                 const float* __restrict__ bias,
                                                 const float* __restrict__ sc,
                                                 const float* __restrict__ ofs,
                                                 u16* __restrict__ out, int col_off) {
  int r = blockIdx.x, t = threadIdx.x;
  ushort4 uv = *(const ushort4*)(F + (size_t)r * ldf + t * 4);
  float4 b4 = *(const float4*)(bias + t * 4);
  float4 v;
  v.x = fmaxf(b2f(uv.x) + b4.x, 0.f);
  v.y = fmaxf(b2f(uv.y) + b4.y, 0.f);
  v.z = fmaxf(b2f(uv.z) + b4.z, 0.f);
  v.w = fmaxf(b2f(uv.w) + b4.w, 0.f);
  float sum = v.x + v.y + v.z + v.w;
  float sq = v.x * v.x + v.y * v.y + v.z * v.z + v.w * v.w;
  for (int d = 32; d > 0; d >>= 1) {
    sum += __shfl_down(sum, d);
    sq  += __shfl_down(sq, d);
  }
  __shared__ float red[4];
  if ((t & 63) == 0) { red[(t >> 6) * 2] = sum; red[(t >> 6) * 2 + 1] = sq; }
  __syncthreads();
  float S = red[0] + red[2], Q = red[1] + red[3];
  float mean = S * (1.f / 512.f);
  float var = Q * (1.f / 512.f) - mean * mean;
  float rstd = rsqrtf(var + 1e-9f);
  float4 s4 = *(const float4*)(sc + t * 4);
  float4 o4 = *(const float4*)(ofs + t * 4);
  ushort4 o;
  o.x = f2b((v.x - mean) * s4.x * rstd + o4.x);
  o.y = f2b((v.y - mean) * s4.y * rstd + o4.y);
  o.z = f2b((v.z - mean) * s4.z * rstd + o4.z);
  o.w = f2b((v.w - mean) * s4.w * rstd + o4.w);
  *(ushort4*)(out + (size_t)r * 1024 + col_off + t * 4) = o;
}

// ---------------- per-row 1/L2-norm of bf16 [NSUB,1024] ----------------
__global__ __launch_bounds__(256) void l2scale(const u16* __restrict__ H,
                                               float* __restrict__ rn) {
  const int lane = threadIdx.x & 63, wave = threadIdx.x >> 6;
  const int r = blockIdx.x * 4 + wave;
  const u16* row = H + (size_t)r * 1024 + lane * 16;
  int4 u0 = *(const int4*)row;
  int4 u1 = *(const int4*)(row + 8);
  float sq = 0.f;
  const int vals[8] = {u0.x, u0.y, u0.z, u0.w, u1.x, u1.y, u1.z, u1.w};
#pragma unroll
  for (int j = 0; j < 8; ++j) {
    u32 wv = (u32)vals[j];
    float f0 = __uint_as_float(wv << 16);
    float f1 = __uint_as_float(wv & 0xffff0000u);
    sq += f0 * f0 + f1 * f1;
  }
#pragma unroll
  for (int d = 1; d < 64; d <<= 1) sq += __shfl_xor(sq, d);
  if (lane == 0) rn[r] = 1.f / fmaxf(sqrtf(sq), 1e-12f);
}

extern "C" void kernel_launch(void* const* d_in, const int* in_sizes, int n_in,
                              void* d_out, int out_size, void* d_ws, size_t ws_size,
                              hipStream_t stream) {
  (void)in_sizes; (void)n_in; (void)out_size; (void)ws_size;
  const float* feat_full = (const float*)d_in[0];
  const int*   nodes = (const int*)d_in[1];
  const int*   arow = (const int*)d_in[2];
  const int*   acol = (const int*)d_in[3];
  const float* aval = (const float*)d_in[4];
  const float* W1_0 = (const float*)d_in[5];
  const float* W1_1 = (const float*)d_in[6];
  const float* b1_0 = (const float*)d_in[7];
  const float* b1_1 = (const float*)d_in[8];
  const float* s1_0 = (const float*)d_in[9];
  const float* s1_1 = (const float*)d_in[10];
  const float* o1_0 = (const float*)d_in[11];
  const float* o1_1 = (const float*)d_in[12];
  const float* W2_0 = (const float*)d_in[13];
  const float* W2_1 = (const float*)d_in[14];
  const float* b2_0 = (const float*)d_in[15];
  const float* b2_1 = (const float*)d_in[16];
  const float* s2_0 = (const float*)d_in[17];
  const float* s2_1 = (const float*)d_in[18];
  const float* o2_0 = (const float*)d_in[19];
  const float* o2_1 = (const float*)d_in[20];
  const float* Wc = (const float*)d_in[21];
  const float* bc = (const float*)d_in[22];
  float* out = (float*)d_out;

  const size_t MB = (size_t)1 << 20;
  char* p = (char*)d_ws;
  u16* FEAT = (u16*)p;                    // 32 MiB [NSUB,512]
  u16* S1   = (u16*)(p + 32 * MB);        // 32 MiB
  u16* H1   = (u16*)(p + 64 * MB);        // 64 MiB [NSUB,1024]
  u16* H2   = (u16*)(p + 128 * MB);       // 64 MiB
  u16* TMPb = (u16*)(p + 192 * MB);       // layer-1 preact [NSUB,512]
  u16* TTL  = (u16*)(p + 192 * MB);       // layer-2 merged preact [NSUB,1024]
  u16* W1_0b = (u16*)(p + 256 * MB);          // 512 KiB
  u16* W1_1b = W1_0b + 512 * 512;             // 512 KiB
  u16* W2cat = W1_1b + 512 * 512;             // [1024,1024] 2 MiB
  u16* Wcb   = W2cat + 1024 * 1024;           // 1 MiB -> ends at 260 MiB
  int* row_off = (int*)(p + 260 * MB);        // 33024 ints
  int* cnt8    = (int*)(p + 261 * MB);        // 262144 ints (1 MiB)
  int* cursor8 = (int*)(p + 262 * MB);        // 1 MiB
  float* RN    = (float*)(p + 263 * MB);      // 128 KiB
  int2* cv     = (int2*)(p + 264 * MB);       // 8 MiB -> ends at 272 MiB

  hipMemsetAsync(cnt8, 0, NSUB * 8 * sizeof(int), stream);

  // weights -> bf16 (W2_0/W2_1 concatenated row-wise into W2cat)
  cvt_bf16<<<(512 * 512 / 4 + 255) / 256, 256, 0, stream>>>(W1_0, W1_0b, 512 * 512 / 4);
  cvt_bf16<<<(512 * 512 / 4 + 255) / 256, 256, 0, stream>>>(W1_1, W1_1b, 512 * 512 / 4);
  cvt_bf16<<<(512 * 1024 / 4 + 255) / 256, 256, 0, stream>>>(W2_0, W2cat, 512 * 1024 / 4);
  cvt_bf16<<<(512 * 1024 / 4 + 255) / 256, 256, 0, stream>>>(W2_1, W2cat + 512 * 1024, 512 * 1024 / 4);
  cvt_bf16<<<(512 * 1024 / 4 + 255) / 256, 256, 0, stream>>>(Wc, Wcb, 512 * 1024 / 4);

  gather_cast<<<NSUB, 128, 0, stream>>>(feat_full, nodes, FEAT);

  // CSR build (column-bucketed for XCD-L2 locality)
  edge_count8<<<NNZ_E / 256, 256, 0, stream>>>(arow, acol, cnt8);
  scan_rows8<<<1, 1024, 0, stream>>>(cnt8, row_off, cursor8);
  edge_scatter8<<<NNZ_E / 256, 256, 0, stream>>>(arow, acol, aval, cursor8, cv);

  // ---- layer 1 ----
  spmm512<512, false><<<NSUB / 4, 256, 0, stream>>>(row_off, cv, FEAT, S1, 512,
                                                    nullptr, nullptr, nullptr);
  gemm_bt<512, 512, false, true, false><<<dim3(4, 256), 256, 0, stream>>>(
      FEAT, W1_0b, nullptr, nullptr, nullptr, TMPb);
  rownorm_b<<<NSUB, 128, 0, stream>>>(TMPb, 512, b1_0, s1_0, o1_0, H1, 0);
  gemm_bt<512, 512, false, true, false><<<dim3(4, 256), 256, 0, stream>>>(
      S1, W1_1b, nullptr, nullptr, nullptr, TMPb);
  rownorm_b<<<NSUB, 128, 0, stream>>>(TMPb, 512, b1_1, s1_1, o1_1, H1, 512);

  // ---- layer 2 (merged GEMM -> TTL; hop0 rownorm; hop1 spmm-norm) ----
  gemm_bt<1024, 1024, false, true, false><<<dim3(8, 256), 256, 0, stream>>>(
      H1, W2cat, nullptr, nullptr, nullptr, TTL);
  rownorm_b<<<NSUB, 128, 0, stream>>>(TTL, 1024, b2_0, s2_0, o2_0, H2, 0);
  spmm512<1024, true><<<NSUB / 4, 256, 0, stream>>>(row_off, cv, TTL + 512, H2 + 512, 1024,
                                                    b2_1, s2_1, o2_1);

  // ---- classifier with folded L2 normalization ----
  l2scale<<<NSUB / 4, 256, 0, stream>>>(H2, RN);
  gemm_bt<1024, 512, true, false, true><<<dim3(4, 256), 256, 0, stream>>>(
      H2, Wcb, bc, RN, out, nullptr);
}

// Round 8
// 684.300 us; speedup vs baseline: 1.3067x; 1.3067x over previous
//
#include <hip/hip_runtime.h>
#include <stdint.h>

typedef unsigned short u16;
typedef unsigned int u32;

#define NSUB 32768
#define NNZ_E 1048576

using short8 = __attribute__((ext_vector_type(8))) short;
using f32x4  = __attribute__((ext_vector_type(4))) float;

__device__ __forceinline__ u16 f2b(float f) {
  u32 u = __float_as_uint(f);
  return (u16)((u + 0x7fffu + ((u >> 16) & 1u)) >> 16);
}
__device__ __forceinline__ float b2f(u16 x) {
  return __uint_as_float(((u32)x) << 16);
}

__device__ __forceinline__ void glds16(const void* g, void* l) {
  __builtin_amdgcn_global_load_lds(
      (const __attribute__((address_space(1))) u32*)g,
      (__attribute__((address_space(3))) u32*)l, 16, 0, 0);
}

// ---------------- weight f32 -> bf16 ----------------
__global__ __launch_bounds__(256) void cvt_bf16(const float* __restrict__ in,
                                                u16* __restrict__ out, int n4) {
  int i = blockIdx.x * 256 + threadIdx.x;
  if (i < n4) {
    float4 v = ((const float4*)in)[i];
    ushort4 o;
    o.x = f2b(v.x); o.y = f2b(v.y); o.z = f2b(v.z); o.w = f2b(v.w);
    ((ushort4*)out)[i] = o;
  }
}

// ---------------- gather + cast ----------------
__global__ __launch_bounds__(128) void gather_cast(const float* __restrict__ ff,
                                                   const int* __restrict__ idx,
                                                   u16* __restrict__ out) {
  int r = blockIdx.x, t = threadIdx.x;
  size_t src = (size_t)idx[r];
  float4 v = *(const float4*)(ff + src * 512 + t * 4);
  ushort4 o;
  o.x = f2b(v.x); o.y = f2b(v.y); o.z = f2b(v.z); o.w = f2b(v.w);
  *(ushort4*)(out + (size_t)r * 512 + t * 4) = o;
}

// ---------------- CSR build, bucketed by column range ----------------
// bucket = col >> 12 (8 buckets of 4096 rows = 4 MiB bf16 = one XCD L2).
__global__ __launch_bounds__(256) void edge_count8(const int* __restrict__ row,
                                                   const int* __restrict__ col,
                                                   int* __restrict__ cnt8) {
  int i = blockIdx.x * 256 + threadIdx.x;
  atomicAdd(&cnt8[row[i] * 8 + (col[i] >> 12)], 1);
}

// 3-phase hierarchical exclusive scan of cnt8[262144]
__global__ __launch_bounds__(256) void scan_part(const int* __restrict__ cnt8,
                                                 int* __restrict__ bsum) {
  int bid = blockIdx.x, t = threadIdx.x;
  int4 c = *(const int4*)(cnt8 + bid * 1024 + t * 4);
  int s = c.x + c.y + c.z + c.w;
#pragma unroll
  for (int d = 1; d < 64; d <<= 1) s += __shfl_xor(s, d);
  __shared__ int red[4];
  if ((t & 63) == 0) red[t >> 6] = s;
  __syncthreads();
  if (t == 0) bsum[bid] = red[0] + red[1] + red[2] + red[3];
}

__global__ __launch_bounds__(256) void scan_top(const int* __restrict__ bsum,
                                                int* __restrict__ boff) {
  int t = threadIdx.x;
  int v = bsum[t];
  int s = v;
#pragma unroll
  for (int d = 1; d < 64; d <<= 1) {
    int u = __shfl_up(s, d);
    if ((t & 63) >= d) s += u;
  }
  __shared__ int wsum[4];
  if ((t & 63) == 63) wsum[t >> 6] = s;
  __syncthreads();
  int add = 0;
  for (int w = 0; w < (t >> 6); ++w) add += wsum[w];
  boff[t] = s + add - v;  // exclusive
}

__global__ __launch_bounds__(256) void scan_final(const int* __restrict__ cnt8,
                                                  const int* __restrict__ boff,
                                                  int* __restrict__ off,
                                                  int* __restrict__ cursor8) {
  int bid = blockIdx.x, t = threadIdx.x;
  int base = bid * 1024 + t * 4;
  int4 c = *(const int4*)(cnt8 + base);
  int s = c.x + c.y + c.z + c.w;
  int inc = s;
#pragma unroll
  for (int d = 1; d < 64; d <<= 1) {
    int u = __shfl_up(inc, d);
    if ((t & 63) >= d) inc += u;
  }
  __shared__ int wsum[4];
  if ((t & 63) == 63) wsum[t >> 6] = inc;
  __syncthreads();
  int add = 0;
  for (int w = 0; w < (t >> 6); ++w) add += wsum[w];
  int run = boff[bid] + inc + add - s;
  int vals[4] = {c.x, c.y, c.z, c.w};
#pragma unroll
  for (int j = 0; j < 4; ++j) {
    int idx = base + j;
    cursor8[idx] = run;
    if ((idx & 7) == 0) off[idx >> 3] = run;
    run += vals[j];
  }
  if (bid == 255 && t == 255) off[NSUB] = run;
}

__global__ __launch_bounds__(256) void edge_scatter8(const int* __restrict__ row,
                                                     const int* __restrict__ col,
                                                     const float* __restrict__ val,
                                                     int* __restrict__ cursor8,
                                                     int2* __restrict__ cv) {
  int i = blockIdx.x * 256 + threadIdx.x;
  int c = col[i];
  int p = atomicAdd(&cursor8[row[i] * 8 + (c >> 12)], 1);
  int2 e; e.x = c; e.y = __float_as_int(val[i]);
  cv[p] = e;
}

// ---------------- SpMM, one wave per row, 16B gathers, MLP=4 ----------------
__device__ __forceinline__ void fma8(int4 u, float v, float* a) {
  u32 w;
  w = (u32)u.x; a[0] += v * __uint_as_float(w << 16); a[1] += v * __uint_as_float(w & 0xffff0000u);
  w = (u32)u.y; a[2] += v * __uint_as_float(w << 16); a[3] += v * __uint_as_float(w & 0xffff0000u);
  w = (u32)u.z; a[4] += v * __uint_as_float(w << 16); a[5] += v * __uint_as_float(w & 0xffff0000u);
  w = (u32)u.w; a[6] += v * __uint_as_float(w << 16); a[7] += v * __uint_as_float(w & 0xffff0000u);
}

// NORM=false: plain aggregated features -> bf16
// NORM=true : fused bias+relu+mean/var-norm -> bf16
template <int LDX, bool NORM>
__global__ __launch_bounds__(256) void spmm512(const int* __restrict__ off,
                                               const int2* __restrict__ cv,
                                               const u16* __restrict__ X,
                                               u16* __restrict__ Y, int ldy,
                                               const float* __restrict__ bias,
                                               const float* __restrict__ sc,
                                               const float* __restrict__ ofs) {
  const int lane = threadIdx.x & 63, wave = threadIdx.x >> 6;
  const int r = blockIdx.x * 4 + wave;
  const int s = __builtin_amdgcn_readfirstlane(off[r]);
  const int e = __builtin_amdgcn_readfirstlane(off[r + 1]);
  float a[8] = {0.f, 0.f, 0.f, 0.f, 0.f, 0.f, 0.f, 0.f};
  const u16* Xl = X + lane * 8;
  int i = s;
  for (; i + 4 <= e; i += 4) {
    int2 p0 = cv[i], p1 = cv[i + 1], p2 = cv[i + 2], p3 = cv[i + 3];
    int4 u0 = *(const int4*)(Xl + (size_t)p0.x * LDX);
    int4 u1 = *(const int4*)(Xl + (size_t)p1.x * LDX);
    int4 u2 = *(const int4*)(Xl + (size_t)p2.x * LDX);
    int4 u3 = *(const int4*)(Xl + (size_t)p3.x * LDX);
    fma8(u0, __int_as_float(p0.y), a);
    fma8(u1, __int_as_float(p1.y), a);
    fma8(u2, __int_as_float(p2.y), a);
    fma8(u3, __int_as_float(p3.y), a);
  }
  for (; i < e; ++i) {
    int2 p0 = cv[i];
    int4 u0 = *(const int4*)(Xl + (size_t)p0.x * LDX);
    fma8(u0, __int_as_float(p0.y), a);
  }
  if (NORM) {
    float4 b0 = *(const float4*)(bias + lane * 8);
    float4 b1 = *(const float4*)(bias + lane * 8 + 4);
    a[0] = fmaxf(a[0] + b0.x, 0.f); a[1] = fmaxf(a[1] + b0.y, 0.f);
    a[2] = fmaxf(a[2] + b0.z, 0.f); a[3] = fmaxf(a[3] + b0.w, 0.f);
    a[4] = fmaxf(a[4] + b1.x, 0.f); a[5] = fmaxf(a[5] + b1.y, 0.f);
    a[6] = fmaxf(a[6] + b1.z, 0.f); a[7] = fmaxf(a[7] + b1.w, 0.f);
    float sum = 0.f, sq = 0.f;
#pragma unroll
    for (int j = 0; j < 8; ++j) { sum += a[j]; sq += a[j] * a[j]; }
#pragma unroll
    for (int d = 1; d < 64; d <<= 1) {
      sum += __shfl_xor(sum, d);
      sq  += __shfl_xor(sq, d);
    }
    float mean = sum * (1.f / 512.f);
    float var = sq * (1.f / 512.f) - mean * mean;
    float rstd = rsqrtf(var + 1e-9f);
    float4 s0 = *(const float4*)(sc + lane * 8);
    float4 s1 = *(const float4*)(sc + lane * 8 + 4);
    float4 o0 = *(const float4*)(ofs + lane * 8);
    float4 o1 = *(const float4*)(ofs + lane * 8 + 4);
    int4 o;
    o.x = (int)((u32)f2b((a[0] - mean) * s0.x * rstd + o0.x) |
                ((u32)f2b((a[1] - mean) * s0.y * rstd + o0.y) << 16));
    o.y = (int)((u32)f2b((a[2] - mean) * s0.z * rstd + o0.z) |
                ((u32)f2b((a[3] - mean) * s0.w * rstd + o0.w) << 16));
    o.z = (int)((u32)f2b((a[4] - mean) * s1.x * rstd + o1.x) |
                ((u32)f2b((a[5] - mean) * s1.y * rstd + o1.y) << 16));
    o.w = (int)((u32)f2b((a[6] - mean) * s1.z * rstd + o1.z) |
                ((u32)f2b((a[7] - mean) * s1.w * rstd + o1.w) << 16));
    *(int4*)(Y + (size_t)r * ldy + lane * 8) = o;
  } else {
    int4 o;
    o.x = (int)((u32)f2b(a[0]) | ((u32)f2b(a[1]) << 16));
    o.y = (int)((u32)f2b(a[2]) | ((u32)f2b(a[3]) << 16));
    o.z = (int)((u32)f2b(a[4]) | ((u32)f2b(a[5]) << 16));
    o.w = (int)((u32)f2b(a[6]) | ((u32)f2b(a[7]) << 16));
    *(int4*)(Y + (size_t)r * ldy + lane * 8) = o;
  }
}

// ---------------- bf16 MFMA GEMM: C[M,N] = A[M,K] @ W[N,K]^T ----------------
// 128x128 tile, glds staging, XCD swizzle. RS: scale acc by rs[row] (L2-norm fold).
template <int K, int LDC, bool BIAS, bool BF16OUT, bool RS>
__global__ __launch_bounds__(256) void gemm_bt(const u16* __restrict__ A,
                                               const u16* __restrict__ W,
                                               const float* __restrict__ bias,
                                               const float* __restrict__ rs,
                                               float* __restrict__ Cf,
                                               u16* __restrict__ Cb) {
  __shared__ __align__(16) u16 As[128 * 32];
  __shared__ __align__(16) u16 Bs[128 * 32];
  const int t = threadIdx.x;
  const int lane = t & 63, wave = t >> 6;
  const int wm = (wave >> 1) * 64, wn = (wave & 1) * 64;
  const int nwg = gridDim.x * gridDim.y;
  const int bid = blockIdx.x + gridDim.x * blockIdx.y;
  const int sbid = (bid % 8) * (nwg / 8) + bid / 8;
  const int bx = sbid % gridDim.x, by = sbid / gridDim.x;
  const int m0 = by * 128, n0 = bx * 128;

  f32x4 acc[4][4];
#pragma unroll
  for (int m = 0; m < 4; ++m)
#pragma unroll
    for (int n = 0; n < 4; ++n) acc[m][n] = f32x4{0.f, 0.f, 0.f, 0.f};

  const int lr = t >> 2;
  const int lc = (t & 3) * 8;
  const u16* Ag  = A + (size_t)(m0 + lr) * K + lc;
  const u16* Ag2 = Ag + (size_t)64 * K;
  const u16* Wg  = W + (size_t)(n0 + lr) * K + lc;
  const u16* Wg2 = Wg + (size_t)64 * K;
  char* asb0 = (char*)As + wave * 1024;
  char* asb1 = (char*)As + 4096 + wave * 1024;
  char* bsb0 = (char*)Bs + wave * 1024;
  char* bsb1 = (char*)Bs + 4096 + wave * 1024;
  const int fr = lane & 15, kh = lane >> 4;

  for (int kt = 0; kt < K / 32; ++kt) {
    glds16(Ag + kt * 32, asb0);
    glds16(Ag2 + kt * 32, asb1);
    glds16(Wg + kt * 32, bsb0);
    glds16(Wg2 + kt * 32, bsb1);
    __syncthreads();
    short8 af[4], bfr[4];
#pragma unroll
    for (int m = 0; m < 4; ++m)
      af[m] = *(const short8*)&As[(wm + m * 16 + fr) * 32 + kh * 8];
#pragma unroll
    for (int n = 0; n < 4; ++n)
      bfr[n] = *(const short8*)&Bs[(wn + n * 16 + fr) * 32 + kh * 8];
#pragma unroll
    for (int m = 0; m < 4; ++m)
#pragma unroll
      for (int n = 0; n < 4; ++n)
        acc[m][n] = __builtin_amdgcn_mfma_f32_16x16x32_bf16(af[m], bfr[n], acc[m][n], 0, 0, 0);
    __syncthreads();
  }

  const int crow = (lane >> 4) * 4;
  const int ccol = lane & 15;
#pragma unroll
  for (int n = 0; n < 4; ++n) {
    int col = n0 + wn + n * 16 + ccol;
    float bv = BIAS ? bias[col] : 0.f;
#pragma unroll
    for (int m = 0; m < 4; ++m) {
      int row = m0 + wm + m * 16 + crow;
#pragma unroll
      for (int q = 0; q < 4; ++q) {
        float v = acc[m][n][q];
        if (RS) v *= rs[row + q];
        v += bv;
        if (BF16OUT)
          Cb[(size_t)(row + q) * LDC + col] = f2b(v);
        else
          Cf[(size_t)(row + q) * LDC + col] = v;
      }
    }
  }
}

// ---------------- fused bias + relu + per-row mean/var norm (bf16 in) ----------------
__global__ __launch_bounds__(128) void rownorm_b(const u16* __restrict__ F, int ldf,
                                                 const float* __restrict__ bias,
                                                 const float* __restrict__ sc,
                                                 const float* __restrict__ ofs,
                                                 u16* __restrict__ out, int col_off) {
  int r = blockIdx.x, t = threadIdx.x;
  ushort4 uv = *(const ushort4*)(F + (size_t)r * ldf + t * 4);
  float4 b4 = *(const float4*)(bias + t * 4);
  float4 v;
  v.x = fmaxf(b2f(uv.x) + b4.x, 0.f);
  v.y = fmaxf(b2f(uv.y) + b4.y, 0.f);
  v.z = fmaxf(b2f(uv.z) + b4.z, 0.f);
  v.w = fmaxf(b2f(uv.w) + b4.w, 0.f);
  float sum = v.x + v.y + v.z + v.w;
  float sq = v.x * v.x + v.y * v.y + v.z * v.z + v.w * v.w;
  for (int d = 32; d > 0; d >>= 1) {
    sum += __shfl_down(sum, d);
    sq  += __shfl_down(sq, d);
  }
  __shared__ float red[4];
  if ((t & 63) == 0) { red[(t >> 6) * 2] = sum; red[(t >> 6) * 2 + 1] = sq; }
  __syncthreads();
  float S = red[0] + red[2], Q = red[1] + red[3];
  float mean = S * (1.f / 512.f);
  float var = Q * (1.f / 512.f) - mean * mean;
  float rstd = rsqrtf(var + 1e-9f);
  float4 s4 = *(const float4*)(sc + t * 4);
  float4 o4 = *(const float4*)(ofs + t * 4);
  ushort4 o;
  o.x = f2b((v.x - mean) * s4.x * rstd + o4.x);
  o.y = f2b((v.y - mean) * s4.y * rstd + o4.y);
  o.z = f2b((v.z - mean) * s4.z * rstd + o4.z);
  o.w = f2b((v.w - mean) * s4.w * rstd + o4.w);
  *(ushort4*)(out + (size_t)r * 1024 + col_off + t * 4) = o;
}

// ---------------- per-row 1/L2-norm of bf16 [NSUB,1024] ----------------
__global__ __launch_bounds__(256) void l2scale(const u16* __restrict__ H,
                                               float* __restrict__ rn) {
  const int lane = threadIdx.x & 63, wave = threadIdx.x >> 6;
  const int r = blockIdx.x * 4 + wave;
  const u16* row = H + (size_t)r * 1024 + lane * 16;
  int4 u0 = *(const int4*)row;
  int4 u1 = *(const int4*)(row + 8);
  float sq = 0.f;
  const int vals[8] = {u0.x, u0.y, u0.z, u0.w, u1.x, u1.y, u1.z, u1.w};
#pragma unroll
  for (int j = 0; j < 8; ++j) {
    u32 wv = (u32)vals[j];
    float f0 = __uint_as_float(wv << 16);
    float f1 = __uint_as_float(wv & 0xffff0000u);
    sq += f0 * f0 + f1 * f1;
  }
#pragma unroll
  for (int d = 1; d < 64; d <<= 1) sq += __shfl_xor(sq, d);
  if (lane == 0) rn[r] = 1.f / fmaxf(sqrtf(sq), 1e-12f);
}

extern "C" void kernel_launch(void* const* d_in, const int* in_sizes, int n_in,
                              void* d_out, int out_size, void* d_ws, size_t ws_size,
                              hipStream_t stream) {
  (void)in_sizes; (void)n_in; (void)out_size; (void)ws_size;
  const float* feat_full = (const float*)d_in[0];
  const int*   nodes = (const int*)d_in[1];
  const int*   arow = (const int*)d_in[2];
  const int*   acol = (const int*)d_in[3];
  const float* aval = (const float*)d_in[4];
  const float* W1_0 = (const float*)d_in[5];
  const float* W1_1 = (const float*)d_in[6];
  const float* b1_0 = (const float*)d_in[7];
  const float* b1_1 = (const float*)d_in[8];
  const float* s1_0 = (const float*)d_in[9];
  const float* s1_1 = (const float*)d_in[10];
  const float* o1_0 = (const float*)d_in[11];
  const float* o1_1 = (const float*)d_in[12];
  const float* W2_0 = (const float*)d_in[13];
  const float* W2_1 = (const float*)d_in[14];
  const float* b2_0 = (const float*)d_in[15];
  const float* b2_1 = (const float*)d_in[16];
  const float* s2_0 = (const float*)d_in[17];
  const float* s2_1 = (const float*)d_in[18];
  const float* o2_0 = (const float*)d_in[19];
  const float* o2_1 = (const float*)d_in[20];
  const float* Wc = (const float*)d_in[21];
  const float* bc = (const float*)d_in[22];
  float* out = (float*)d_out;

  const size_t MB = (size_t)1 << 20;
  char* p = (char*)d_ws;
  u16* FEAT = (u16*)p;                    // 32 MiB [NSUB,512]
  u16* S1   = (u16*)(p + 32 * MB);        // 32 MiB
  u16* H1   = (u16*)(p + 64 * MB);        // 64 MiB [NSUB,1024]
  u16* H2   = (u16*)(p + 128 * MB);       // 64 MiB
  u16* TMPb = (u16*)(p + 192 * MB);       // layer-1 preact [NSUB,512]
  u16* TTL  = (u16*)(p + 192 * MB);       // layer-2 merged preact [NSUB,1024]
  u16* W1_0b = (u16*)(p + 256 * MB);          // 512 KiB
  u16* W1_1b = W1_0b + 512 * 512;             // 512 KiB
  u16* W2cat = W1_1b + 512 * 512;             // [1024,1024] 2 MiB
  u16* Wcb   = W2cat + 1024 * 1024;           // 1 MiB -> ends at 260 MiB
  int* row_off = (int*)(p + 260 * MB);        // 33024 ints
  int* cnt8    = (int*)(p + 261 * MB);        // 262144 ints (1 MiB)
  int* cursor8 = (int*)(p + 262 * MB);        // 1 MiB
  float* RN    = (float*)(p + 263 * MB);      // 128 KiB
  int* bsum    = (int*)((char*)RN + 256 * 1024);  // 256 ints
  int* boff    = bsum + 256;
  int2* cv     = (int2*)(p + 264 * MB);       // 8 MiB -> ends at 272 MiB

  hipMemsetAsync(cnt8, 0, NSUB * 8 * sizeof(int), stream);

  // weights -> bf16 (W2_0/W2_1 concatenated row-wise into W2cat)
  cvt_bf16<<<(512 * 512 / 4 + 255) / 256, 256, 0, stream>>>(W1_0, W1_0b, 512 * 512 / 4);
  cvt_bf16<<<(512 * 512 / 4 + 255) / 256, 256, 0, stream>>>(W1_1, W1_1b, 512 * 512 / 4);
  cvt_bf16<<<(512 * 1024 / 4 + 255) / 256, 256, 0, stream>>>(W2_0, W2cat, 512 * 1024 / 4);
  cvt_bf16<<<(512 * 1024 / 4 + 255) / 256, 256, 0, stream>>>(W2_1, W2cat + 512 * 1024, 512 * 1024 / 4);
  cvt_bf16<<<(512 * 1024 / 4 + 255) / 256, 256, 0, stream>>>(Wc, Wcb, 512 * 1024 / 4);

  gather_cast<<<NSUB, 128, 0, stream>>>(feat_full, nodes, FEAT);

  // CSR build (column-bucketed for XCD-L2 locality; hierarchical scan)
  edge_count8<<<NNZ_E / 256, 256, 0, stream>>>(arow, acol, cnt8);
  scan_part<<<256, 256, 0, stream>>>(cnt8, bsum);
  scan_top<<<1, 256, 0, stream>>>(bsum, boff);
  scan_final<<<256, 256, 0, stream>>>(cnt8, boff, row_off, cursor8);
  edge_scatter8<<<NNZ_E / 256, 256, 0, stream>>>(arow, acol, aval, cursor8, cv);

  // ---- layer 1 ----
  spmm512<512, false><<<NSUB / 4, 256, 0, stream>>>(row_off, cv, FEAT, S1, 512,
                                                    nullptr, nullptr, nullptr);
  gemm_bt<512, 512, false, true, false><<<dim3(4, 256), 256, 0, stream>>>(
      FEAT, W1_0b, nullptr, nullptr, nullptr, TMPb);
  rownorm_b<<<NSUB, 128, 0, stream>>>(TMPb, 512, b1_0, s1_0, o1_0, H1, 0);
  gemm_bt<512, 512, false, true, false><<<dim3(4, 256), 256, 0, stream>>>(
      S1, W1_1b, nullptr, nullptr, nullptr, TMPb);
  rownorm_b<<<NSUB, 128, 0, stream>>>(TMPb, 512, b1_1, s1_1, o1_1, H1, 512);

  // ---- layer 2 (merged GEMM -> TTL; hop0 rownorm; hop1 spmm-norm) ----
  gemm_bt<1024, 1024, false, true, false><<<dim3(8, 256), 256, 0, stream>>>(
      H1, W2cat, nullptr, nullptr, nullptr, TTL);
  rownorm_b<<<NSUB, 128, 0, stream>>>(TTL, 1024, b2_0, s2_0, o2_0, H2, 0);
  spmm512<1024, true><<<NSUB / 4, 256, 0, stream>>>(row_off, cv, TTL + 512, H2 + 512, 1024,
                                                    b2_1, s2_1, o2_1);

  // ---- classifier with folded L2 normalization ----
  l2scale<<<NSUB / 4, 256, 0, stream>>>(H2, RN);
  gemm_bt<1024, 512, true, false, true><<<dim3(4, 256), 256, 0, stream>>>(
      H2, Wcb, bc, RN, out, nullptr);
}

// Round 10
// 655.169 us; speedup vs baseline: 1.3648x; 1.0445x over previous
//
#include <hip/hip_runtime.h>
#include <stdint.h>

typedef unsigned short u16;
typedef unsigned int u32;

#define NSUB 32768
#define NNZ_E 1048576

using short8 = __attribute__((ext_vector_type(8))) short;
using f32x4  = __attribute__((ext_vector_type(4))) float;

__device__ __forceinline__ u16 f2b(float f) {
  u32 u = __float_as_uint(f);
  return (u16)((u + 0x7fffu + ((u >> 16) & 1u)) >> 16);
}
__device__ __forceinline__ float b2f(u16 x) {
  return __uint_as_float(((u32)x) << 16);
}

__device__ __forceinline__ void glds16(const void* g, void* l) {
  __builtin_amdgcn_global_load_lds(
      (const __attribute__((address_space(1))) u32*)g,
      (__attribute__((address_space(3))) u32*)l, 16, 0, 0);
}

// ============ U_prep: gather ∥ edge-count ∥ 5x weight-cast ============
#define GATHER_B 16384
#define COUNT_B 4096
__global__ __launch_bounds__(256) void u_prep(
    const float* __restrict__ ff, const int* __restrict__ idx, u16* __restrict__ FEAT,
    const int* __restrict__ arow, const int* __restrict__ acol, int* __restrict__ cnt8,
    const float* W1_0, const float* W1_1, const float* W2_0, const float* W2_1,
    const float* Wc, u16* W1_0b, u16* W1_1b, u16* W2cat, u16* Wcb) {
  int bid = blockIdx.x, t = threadIdx.x;
  if (bid < GATHER_B) {
    int r = bid * 2 + (t >> 7);
    int c = (t & 127) * 4;
    size_t src = (size_t)idx[r];
    float4 v = *(const float4*)(ff + src * 512 + c);
    ushort4 o;
    o.x = f2b(v.x); o.y = f2b(v.y); o.z = f2b(v.z); o.w = f2b(v.w);
    *(ushort4*)(FEAT + (size_t)r * 512 + c) = o;
  } else if (bid < GATHER_B + COUNT_B) {
    int i = (bid - GATHER_B) * 256 + t;
    atomicAdd(&cnt8[arow[i] * 8 + (acol[i] >> 12)], 1);
  } else {
    int cid = bid - GATHER_B - COUNT_B;
    const float* src; u16* dst; int i;
    if (cid < 256)       { src = W1_0; dst = W1_0b;              i = cid * 256 + t; }
    else if (cid < 512)  { src = W1_1; dst = W1_1b;              i = (cid - 256) * 256 + t; }
    else if (cid < 1024) { src = W2_0; dst = W2cat;              i = (cid - 512) * 256 + t; }
    else if (cid < 1536) { src = W2_1; dst = W2cat + 512 * 1024; i = (cid - 1024) * 256 + t; }
    else                 { src = Wc;   dst = Wcb;                i = (cid - 1536) * 256 + t; }
    float4 v = ((const float4*)src)[i];
    ushort4 o;
    o.x = f2b(v.x); o.y = f2b(v.y); o.z = f2b(v.z); o.w = f2b(v.w);
    ((ushort4*)dst)[i] = o;
  }
}

// ============ hierarchical scan of cnt8[262144] ============
__global__ __launch_bounds__(256) void scan_part(const int* __restrict__ cnt8,
                                                 int* __restrict__ bsum) {
  int bid = blockIdx.x, t = threadIdx.x;
  int4 c = *(const int4*)(cnt8 + bid * 1024 + t * 4);
  int s = c.x + c.y + c.z + c.w;
#pragma unroll
  for (int d = 1; d < 64; d <<= 1) s += __shfl_xor(s, d);
  __shared__ int red[4];
  if ((t & 63) == 0) red[t >> 6] = s;
  __syncthreads();
  if (t == 0) bsum[bid] = red[0] + red[1] + red[2] + red[3];
}

__global__ __launch_bounds__(256) void scan_top(const int* __restrict__ bsum,
                                                int* __restrict__ boff) {
  int t = threadIdx.x;
  int v = bsum[t];
  int s = v;
#pragma unroll
  for (int d = 1; d < 64; d <<= 1) {
    int u = __shfl_up(s, d);
    if ((t & 63) >= d) s += u;
  }
  __shared__ int wsum[4];
  if ((t & 63) == 63) wsum[t >> 6] = s;
  __syncthreads();
  int add = 0;
  for (int w = 0; w < (t >> 6); ++w) add += wsum[w];
  boff[t] = s + add - v;  // exclusive
}

__global__ __launch_bounds__(256) void scan_final(const int* __restrict__ cnt8,
                                                  const int* __restrict__ boff,
                                                  int* __restrict__ off,
                                                  int* __restrict__ cursor8) {
  int bid = blockIdx.x, t = threadIdx.x;
  int base = bid * 1024 + t * 4;
  int4 c = *(const int4*)(cnt8 + base);
  int s = c.x + c.y + c.z + c.w;
  int inc = s;
#pragma unroll
  for (int d = 1; d < 64; d <<= 1) {
    int u = __shfl_up(inc, d);
    if ((t & 63) >= d) inc += u;
  }
  __shared__ int wsum[4];
  if ((t & 63) == 63) wsum[t >> 6] = inc;
  __syncthreads();
  int add = 0;
  for (int w = 0; w < (t >> 6); ++w) add += wsum[w];
  int run = boff[bid] + inc + add - s;
  int vals[4] = {c.x, c.y, c.z, c.w};
#pragma unroll
  for (int j = 0; j < 4; ++j) {
    int idx = base + j;
    cursor8[idx] = run;
    if ((idx & 7) == 0) off[idx >> 3] = run;
    run += vals[j];
  }
  if (bid == 255 && t == 255) off[NSUB] = run;
}

__global__ __launch_bounds__(256) void edge_scatter8(const int* __restrict__ row,
                                                     const int* __restrict__ col,
                                                     const float* __restrict__ val,
                                                     int* __restrict__ cursor8,
                                                     int2* __restrict__ cv) {
  int i = blockIdx.x * 256 + threadIdx.x;
  int c = col[i];
  int p = atomicAdd(&cursor8[row[i] * 8 + (c >> 12)], 1);
  int2 e; e.x = c; e.y = __float_as_int(val[i]);
  cv[p] = e;
}

// ============ shared epilogue: bias+relu+mean/var-norm of one 512-col row ============
__device__ __forceinline__ void norm_rowstore(float* a, int lane, int r,
                                              const float* __restrict__ bias,
                                              const float* __restrict__ sc,
                                              const float* __restrict__ ofs,
                                              u16* __restrict__ Y, int ldy, int col_off) {
  float4 b0 = *(const float4*)(bias + lane * 8);
  float4 b1 = *(const float4*)(bias + lane * 8 + 4);
  a[0] = fmaxf(a[0] + b0.x, 0.f); a[1] = fmaxf(a[1] + b0.y, 0.f);
  a[2] = fmaxf(a[2] + b0.z, 0.f); a[3] = fmaxf(a[3] + b0.w, 0.f);
  a[4] = fmaxf(a[4] + b1.x, 0.f); a[5] = fmaxf(a[5] + b1.y, 0.f);
  a[6] = fmaxf(a[6] + b1.z, 0.f); a[7] = fmaxf(a[7] + b1.w, 0.f);
  float sum = 0.f, sq = 0.f;
#pragma unroll
  for (int j = 0; j < 8; ++j) { sum += a[j]; sq += a[j] * a[j]; }
#pragma unroll
  for (int d = 1; d < 64; d <<= 1) {
    sum += __shfl_xor(sum, d);
    sq  += __shfl_xor(sq, d);
  }
  float mean = sum * (1.f / 512.f);
  float var = sq * (1.f / 512.f) - mean * mean;
  float rstd = rsqrtf(var + 1e-9f);
  float4 s0 = *(const float4*)(sc + lane * 8);
  float4 s1 = *(const float4*)(sc + lane * 8 + 4);
  float4 o0 = *(const float4*)(ofs + lane * 8);
  float4 o1 = *(const float4*)(ofs + lane * 8 + 4);
  int4 o;
  o.x = (int)((u32)f2b((a[0] - mean) * s0.x * rstd + o0.x) |
              ((u32)f2b((a[1] - mean) * s0.y * rstd + o0.y) << 16));
  o.y = (int)((u32)f2b((a[2] - mean) * s0.z * rstd + o0.z) |
              ((u32)f2b((a[3] - mean) * s0.w * rstd + o0.w) << 16));
  o.z = (int)((u32)f2b((a[4] - mean) * s1.x * rstd + o1.x) |
              ((u32)f2b((a[5] - mean) * s1.y * rstd + o1.y) << 16));
  o.w = (int)((u32)f2b((a[6] - mean) * s1.z * rstd + o1.z) |
              ((u32)f2b((a[7] - mean) * s1.w * rstd + o1.w) << 16));
  *(int4*)(Y + (size_t)r * ldy + col_off + lane * 8) = o;
}

// ============ SpMM, one wave per row, 16B gathers, MLP=4 ============
__device__ __forceinline__ void fma8(int4 u, float v, float* a) {
  u32 w;
  w = (u32)u.x; a[0] += v * __uint_as_float(w << 16); a[1] += v * __uint_as_float(w & 0xffff0000u);
  w = (u32)u.y; a[2] += v * __uint_as_float(w << 16); a[3] += v * __uint_as_float(w & 0xffff0000u);
  w = (u32)u.z; a[4] += v * __uint_as_float(w << 16); a[5] += v * __uint_as_float(w & 0xffff0000u);
  w = (u32)u.w; a[6] += v * __uint_as_float(w << 16); a[7] += v * __uint_as_float(w & 0xffff0000u);
}

template <int LDX, bool NORM>
__device__ __forceinline__ void spmm_dev(const int* __restrict__ off,
                                         const int2* __restrict__ cv,
                                         const u16* __restrict__ X,
                                         u16* __restrict__ Y, int ldy, int col_off,
                                         const float* __restrict__ bias,
                                         const float* __restrict__ sc,
                                         const float* __restrict__ ofs, int bid) {
  const int lane = threadIdx.x & 63, wave = threadIdx.x >> 6;
  const int r = bid * 4 + wave;
  const int s = __builtin_amdgcn_readfirstlane(off[r]);
  const int e = __builtin_amdgcn_readfirstlane(off[r + 1]);
  float a[8] = {0.f, 0.f, 0.f, 0.f, 0.f, 0.f, 0.f, 0.f};
  const u16* Xl = X + lane * 8;
  int i = s;
  for (; i + 4 <= e; i += 4) {
    int2 p0 = cv[i], p1 = cv[i + 1], p2 = cv[i + 2], p3 = cv[i + 3];
    int4 u0 = *(const int4*)(Xl + (size_t)p0.x * LDX);
    int4 u1 = *(const int4*)(Xl + (size_t)p1.x * LDX);
    int4 u2 = *(const int4*)(Xl + (size_t)p2.x * LDX);
    int4 u3 = *(const int4*)(Xl + (size_t)p3.x * LDX);
    fma8(u0, __int_as_float(p0.y), a);
    fma8(u1, __int_as_float(p1.y), a);
    fma8(u2, __int_as_float(p2.y), a);
    fma8(u3, __int_as_float(p3.y), a);
  }
  for (; i < e; ++i) {
    int2 p0 = cv[i];
    int4 u0 = *(const int4*)(Xl + (size_t)p0.x * LDX);
    fma8(u0, __int_as_float(p0.y), a);
  }
  if (NORM) {
    norm_rowstore(a, lane, r, bias, sc, ofs, Y, ldy, col_off);
  } else {
    int4 o;
    o.x = (int)((u32)f2b(a[0]) | ((u32)f2b(a[1]) << 16));
    o.y = (int)((u32)f2b(a[2]) | ((u32)f2b(a[3]) << 16));
    o.z = (int)((u32)f2b(a[4]) | ((u32)f2b(a[5]) << 16));
    o.w = (int)((u32)f2b(a[6]) | ((u32)f2b(a[7]) << 16));
    *(int4*)(Y + (size_t)r * ldy + col_off + lane * 8) = o;
  }
}

__global__ __launch_bounds__(256) void spmm1_k(const int* __restrict__ off,
                                               const int2* __restrict__ cv,
                                               const u16* __restrict__ X,
                                               u16* __restrict__ Y) {
  spmm_dev<512, false>(off, cv, X, Y, 512, 0, nullptr, nullptr, nullptr, blockIdx.x);
}

// ============ wave-per-row rownorm (bf16 in) ============
__device__ __forceinline__ void rownorm_dev(const u16* __restrict__ F, int ldf,
                                            const float* __restrict__ bias,
                                            const float* __restrict__ sc,
                                            const float* __restrict__ ofs,
                                            u16* __restrict__ Y, int ldy, int col_off,
                                            int bid) {
  const int lane = threadIdx.x & 63, wave = threadIdx.x >> 6;
  const int r = bid * 4 + wave;
  int4 u = *(const int4*)(F + (size_t)r * ldf + lane * 8);
  float a[8];
  a[0] = __uint_as_float(((u32)u.x) << 16); a[1] = __uint_as_float(((u32)u.x) & 0xffff0000u);
  a[2] = __uint_as_float(((u32)u.y) << 16); a[3] = __uint_as_float(((u32)u.y) & 0xffff0000u);
  a[4] = __uint_as_float(((u32)u.z) << 16); a[5] = __uint_as_float(((u32)u.z) & 0xffff0000u);
  a[6] = __uint_as_float(((u32)u.w) << 16); a[7] = __uint_as_float(((u32)u.w) & 0xffff0000u);
  norm_rowstore(a, lane, r, bias, sc, ofs, Y, ldy, col_off);
}

__global__ __launch_bounds__(256) void rownorm_k(const u16* __restrict__ F, int ldf,
                                                 const float* __restrict__ bias,
                                                 const float* __restrict__ sc,
                                                 const float* __restrict__ ofs,
                                                 u16* __restrict__ Y, int col_off) {
  rownorm_dev(F, ldf, bias, sc, ofs, Y, 1024, col_off, blockIdx.x);
}

// ============ U_l2: spmm2(+norm) ∥ rownorm2-hop0 ============
__global__ __launch_bounds__(256) void u_l2(const int* __restrict__ row_off,
                                            const int2* __restrict__ cv,
                                            const u16* __restrict__ TTL,
                                            u16* __restrict__ H2,
                                            const float* __restrict__ b2_0,
                                            const float* __restrict__ s2_0,
                                            const float* __restrict__ o2_0,
                                            const float* __restrict__ b2_1,
                                            const float* __restrict__ s2_1,
                                            const float* __restrict__ o2_1) {
  int bid = blockIdx.x;
  if (bid < 8192)
    spmm_dev<1024, true>(row_off, cv, TTL + 512, H2, 1024, 512, b2_1, s2_1, o2_1, bid);
  else
    rownorm_dev(TTL, 1024, b2_0, s2_0, o2_0, H2, 1024, 0, bid - 8192);
}

// ============ bf16 MFMA GEMM: C[M,N] = A[M,K] @ W[N,K]^T ============
// 128x128 tile, glds staging, XCD swizzle. RS: scale acc by rs[row] (L2-norm fold).
template <int K, int LDC, bool BIAS, bool BF16OUT, bool RS>
__global__ __launch_bounds__(256) void gemm_bt(const u16* __restrict__ A,
                                               const u16* __restrict__ W,
                                               const float* __restrict__ bias,
                                               const float* __restrict__ rs,
                                               float* __restrict__ Cf,
                                               u16* __restrict__ Cb) {
  __shared__ __align__(16) u16 As[128 * 32];
  __shared__ __align__(16) u16 Bs[128 * 32];
  const int t = threadIdx.x;
  const int lane = t & 63, wave = t >> 6;
  const int wm = (wave >> 1) * 64, wn = (wave & 1) * 64;
  const int nwg = gridDim.x * gridDim.y;
  const int bid = blockIdx.x + gridDim.x * blockIdx.y;
  const int sbid = (bid % 8) * (nwg / 8) + bid / 8;
  const int bx = sbid % gridDim.x, by = sbid / gridDim.x;
  const int m0 = by * 128, n0 = bx * 128;

  f32x4 acc[4][4];
#pragma unroll
  for (int m = 0; m < 4; ++m)
#pragma unroll
    for (int n = 0; n < 4; ++n) acc[m][n] = f32x4{0.f, 0.f, 0.f, 0.f};

  const int lr = t >> 2;
  const int lc = (t & 3) * 8;
  const u16* Ag  = A + (size_t)(m0 + lr) * K + lc;
  const u16* Ag2 = Ag + (size_t)64 * K;
  const u16* Wg  = W + (size_t)(n0 + lr) * K + lc;
  const u16* Wg2 = Wg + (size_t)64 * K;
  char* asb0 = (char*)As + wave * 1024;
  char* asb1 = (char*)As + 4096 + wave * 1024;
  char* bsb0 = (char*)Bs + wave * 1024;
  char* bsb1 = (char*)Bs + 4096 + wave * 1024;
  const int fr = lane & 15, kh = lane >> 4;

  for (int kt = 0; kt < K / 32; ++kt) {
    glds16(Ag + kt * 32, asb0);
    glds16(Ag2 + kt * 32, asb1);
    glds16(Wg + kt * 32, bsb0);
    glds16(Wg2 + kt * 32, bsb1);
    __syncthreads();
    short8 af[4], bfr[4];
#pragma unroll
    for (int m = 0; m < 4; ++m)
      af[m] = *(const short8*)&As[(wm + m * 16 + fr) * 32 + kh * 8];
#pragma unroll
    for (int n = 0; n < 4; ++n)
      bfr[n] = *(const short8*)&Bs[(wn + n * 16 + fr) * 32 + kh * 8];
#pragma unroll
    for (int m = 0; m < 4; ++m)
#pragma unroll
      for (int n = 0; n < 4; ++n)
        acc[m][n] = __builtin_amdgcn_mfma_f32_16x16x32_bf16(af[m], bfr[n], acc[m][n], 0, 0, 0);
    __syncthreads();
  }

  const int crow = (lane >> 4) * 4;  // C/D: row=(lane>>4)*4+reg, col=lane&15
  const int ccol = lane & 15;
#pragma unroll
  for (int n = 0; n < 4; ++n) {
    int col = n0 + wn + n * 16 + ccol;
    float bv = BIAS ? bias[col] : 0.f;
#pragma unroll
    for (int m = 0; m < 4; ++m) {
      int row = m0 + wm + m * 16 + crow;
#pragma unroll
      for (int q = 0; q < 4; ++q) {
        float v = acc[m][n][q];
        if (RS) v *= rs[row + q];
        v += bv;
        if (BF16OUT)
          Cb[(size_t)(row + q) * LDC + col] = f2b(v);
        else
          Cf[(size_t)(row + q) * LDC + col] = v;
      }
    }
  }
}

// ============ per-row 1/L2-norm of bf16 [NSUB,1024] ============
__global__ __launch_bounds__(256) void l2scale(const u16* __restrict__ H,
                                               float* __restrict__ rn) {
  const int lane = threadIdx.x & 63, wave = threadIdx.x >> 6;
  const int r = blockIdx.x * 4 + wave;
  const u16* row = H + (size_t)r * 1024 + lane * 16;
  int4 u0 = *(const int4*)row;
  int4 u1 = *(const int4*)(row + 8);
  float sq = 0.f;
  const int vals[8] = {u0.x, u0.y, u0.z, u0.w, u1.x, u1.y, u1.z, u1.w};
#pragma unroll
  for (int j = 0; j < 8; ++j) {
    u32 wv = (u32)vals[j];
    float f0 = __uint_as_float(wv << 16);
    float f1 = __uint_as_float(wv & 0xffff0000u);
    sq += f0 * f0 + f1 * f1;
  }
#pragma unroll
  for (int d = 1; d < 64; d <<= 1) sq += __shfl_xor(sq, d);
  if (lane == 0) rn[r] = 1.f / fmaxf(sqrtf(sq), 1e-12f);
}

extern "C" void kernel_launch(void* const* d_in, const int* in_sizes, int n_in,
                              void* d_out, int out_size, void* d_ws, size_t ws_size,
                              hipStream_t stream) {
  (void)in_sizes; (void)n_in; (void)out_size; (void)ws_size;
  const float* feat_full = (const float*)d_in[0];
  const int*   nodes = (const int*)d_in[1];
  const int*   arow = (const int*)d_in[2];
  const int*   acol = (const int*)d_in[3];
  const float* aval = (const float*)d_in[4];
  const float* W1_0 = (const float*)d_in[5];
  const float* W1_1 = (const float*)d_in[6];
  const float* b1_0 = (const float*)d_in[7];
  const float* b1_1 = (const float*)d_in[8];
  const float* s1_0 = (const float*)d_in[9];
  const float* s1_1 = (const float*)d_in[10];
  const float* o1_0 = (const float*)d_in[11];
  const float* o1_1 = (const float*)d_in[12];
  const float* W2_0 = (const float*)d_in[13];
  const float* W2_1 = (const float*)d_in[14];
  const float* b2_0 = (const float*)d_in[15];
  const float* b2_1 = (const float*)d_in[16];
  const float* s2_0 = (const float*)d_in[17];
  const float* s2_1 = (const float*)d_in[18];
  const float* o2_0 = (const float*)d_in[19];
  const float* o2_1 = (const float*)d_in[20];
  const float* Wc = (const float*)d_in[21];
  const float* bc = (const float*)d_in[22];
  float* out = (float*)d_out;

  const size_t MB = (size_t)1 << 20;
  char* p = (char*)d_ws;
  u16* FEAT = (u16*)p;                    // 32 MiB [NSUB,512]
  u16* S1   = (u16*)(p + 32 * MB);        // 32 MiB
  u16* H1   = (u16*)(p + 64 * MB);        // 64 MiB [NSUB,1024]
  u16* H2   = (u16*)(p + 128 * MB);       // 64 MiB
  u16* TMPb = (u16*)(p + 192 * MB);       // layer-1 preact [NSUB,512]
  u16* TTL  = (u16*)(p + 192 * MB);       // layer-2 merged preact [NSUB,1024]
  u16* W1_0b = (u16*)(p + 256 * MB);
  u16* W1_1b = W1_0b + 512 * 512;
  u16* W2cat = W1_1b + 512 * 512;         // [1024,1024]
  u16* Wcb   = W2cat + 1024 * 1024;
  int* row_off = (int*)(p + 260 * MB);
  int* cnt8    = (int*)(p + 261 * MB);
  int* cursor8 = (int*)(p + 262 * MB);
  float* RN    = (float*)(p + 263 * MB);
  int* bsum    = (int*)((char*)RN + 256 * 1024);
  int* boff    = bsum + 256;
  int2* cv     = (int2*)(p + 264 * MB);

  hipMemsetAsync(cnt8, 0, NSUB * 8 * sizeof(int), stream);

  // prep: gather ∥ edge-count ∥ weight casts
  u_prep<<<GATHER_B + COUNT_B + 2048, 256, 0, stream>>>(
      feat_full, nodes, FEAT, arow, acol, cnt8,
      W1_0, W1_1, W2_0, W2_1, Wc, W1_0b, W1_1b, W2cat, Wcb);

  scan_part<<<256, 256, 0, stream>>>(cnt8, bsum);
  scan_top<<<1, 256, 0, stream>>>(bsum, boff);
  scan_final<<<256, 256, 0, stream>>>(cnt8, boff, row_off, cursor8);
  edge_scatter8<<<NNZ_E / 256, 256, 0, stream>>>(arow, acol, aval, cursor8, cv);

  // ---- layer 1 (round-8 structure) ----
  spmm1_k<<<NSUB / 4, 256, 0, stream>>>(row_off, cv, FEAT, S1);
  gemm_bt<512, 512, false, true, false><<<dim3(4, 256), 256, 0, stream>>>(
      FEAT, W1_0b, nullptr, nullptr, nullptr, TMPb);
  rownorm_k<<<NSUB / 4, 256, 0, stream>>>(TMPb, 512, b1_0, s1_0, o1_0, H1, 0);
  gemm_bt<512, 512, false, true, false><<<dim3(4, 256), 256, 0, stream>>>(
      S1, W1_1b, nullptr, nullptr, nullptr, TMPb);
  rownorm_k<<<NSUB / 4, 256, 0, stream>>>(TMPb, 512, b1_1, s1_1, o1_1, H1, 512);

  // ---- layer 2 (merged GEMM -> TTL; union spmm2+norm ∥ rownorm2-hop0) ----
  gemm_bt<1024, 1024, false, true, false><<<dim3(8, 256), 256, 0, stream>>>(
      H1, W2cat, nullptr, nullptr, nullptr, TTL);
  u_l2<<<8192 + 8192, 256, 0, stream>>>(row_off, cv, TTL, H2,
                                        b2_0, s2_0, o2_0, b2_1, s2_1, o2_1);

  // ---- classifier with folded L2 normalization ----
  l2scale<<<NSUB / 4, 256, 0, stream>>>(H2, RN);
  gemm_bt<1024, 512, true, false, true><<<dim3(4, 256), 256, 0, stream>>>(
      H2, Wcb, bc, RN, out, nullptr);
}

// Round 11
// 639.103 us; speedup vs baseline: 1.3991x; 1.0251x over previous
//
#include <hip/hip_runtime.h>
#include <stdint.h>

typedef unsigned short u16;
typedef unsigned int u32;

#define NSUB 32768
#define NNZ_E 1048576

using short8 = __attribute__((ext_vector_type(8))) short;
using f32x4  = __attribute__((ext_vector_type(4))) float;

__device__ __forceinline__ u16 f2b(float f) {
  u32 u = __float_as_uint(f);
  return (u16)((u + 0x7fffu + ((u >> 16) & 1u)) >> 16);
}
__device__ __forceinline__ float b2f(u16 x) {
  return __uint_as_float(((u32)x) << 16);
}

__device__ __forceinline__ void glds16(const void* g, void* l) {
  __builtin_amdgcn_global_load_lds(
      (const __attribute__((address_space(1))) u32*)g,
      (__attribute__((address_space(3))) u32*)l, 16, 0, 0);
}

// ============ U_prep: gather ∥ edge-count ∥ 5x weight-cast ============
#define GATHER_B 16384
#define COUNT_B 4096
__global__ __launch_bounds__(256) void u_prep(
    const float* __restrict__ ff, const int* __restrict__ idx, u16* __restrict__ FEAT,
    const int* __restrict__ arow, const int* __restrict__ acol, int* __restrict__ cnt8,
    const float* W1_0, const float* W1_1, const float* W2_0, const float* W2_1,
    const float* Wc, u16* W1_0b, u16* W1_1b, u16* W2cat, u16* Wcb) {
  int bid = blockIdx.x, t = threadIdx.x;
  if (bid < GATHER_B) {
    int r = bid * 2 + (t >> 7);
    int c = (t & 127) * 4;
    size_t src = (size_t)idx[r];
    float4 v = *(const float4*)(ff + src * 512 + c);
    ushort4 o;
    o.x = f2b(v.x); o.y = f2b(v.y); o.z = f2b(v.z); o.w = f2b(v.w);
    *(ushort4*)(FEAT + (size_t)r * 512 + c) = o;
  } else if (bid < GATHER_B + COUNT_B) {
    int i = (bid - GATHER_B) * 256 + t;
    atomicAdd(&cnt8[arow[i] * 8 + (acol[i] >> 12)], 1);
  } else {
    int cid = bid - GATHER_B - COUNT_B;
    const float* src; u16* dst; int i;
    if (cid < 256)       { src = W1_0; dst = W1_0b;              i = cid * 256 + t; }
    else if (cid < 512)  { src = W1_1; dst = W1_1b;              i = (cid - 256) * 256 + t; }
    else if (cid < 1024) { src = W2_0; dst = W2cat;              i = (cid - 512) * 256 + t; }
    else if (cid < 1536) { src = W2_1; dst = W2cat + 512 * 1024; i = (cid - 1024) * 256 + t; }
    else                 { src = Wc;   dst = Wcb;                i = (cid - 1536) * 256 + t; }
    float4 v = ((const float4*)src)[i];
    ushort4 o;
    o.x = f2b(v.x); o.y = f2b(v.y); o.z = f2b(v.z); o.w = f2b(v.w);
    ((ushort4*)dst)[i] = o;
  }
}

// ============ hierarchical scan of cnt8[262144] ============
__global__ __launch_bounds__(256) void scan_part(const int* __restrict__ cnt8,
                                                 int* __restrict__ bsum) {
  int bid = blockIdx.x, t = threadIdx.x;
  int4 c = *(const int4*)(cnt8 + bid * 1024 + t * 4);
  int s = c.x + c.y + c.z + c.w;
#pragma unroll
  for (int d = 1; d < 64; d <<= 1) s += __shfl_xor(s, d);
  __shared__ int red[4];
  if ((t & 63) == 0) red[t >> 6] = s;
  __syncthreads();
  if (t == 0) bsum[bid] = red[0] + red[1] + red[2] + red[3];
}

__global__ __launch_bounds__(256) void scan_top(const int* __restrict__ bsum,
                                                int* __restrict__ boff) {
  int t = threadIdx.x;
  int v = bsum[t];
  int s = v;
#pragma unroll
  for (int d = 1; d < 64; d <<= 1) {
    int u = __shfl_up(s, d);
    if ((t & 63) >= d) s += u;
  }
  __shared__ int wsum[4];
  if ((t & 63) == 63) wsum[t >> 6] = s;
  __syncthreads();
  int add = 0;
  for (int w = 0; w < (t >> 6); ++w) add += wsum[w];
  boff[t] = s + add - v;  // exclusive
}

__global__ __launch_bounds__(256) void scan_final(const int* __restrict__ cnt8,
                                                  const int* __restrict__ boff,
                                                  int* __restrict__ off,
                                                  int* __restrict__ cursor8) {
  int bid = blockIdx.x, t = threadIdx.x;
  int base = bid * 1024 + t * 4;
  int4 c = *(const int4*)(cnt8 + base);
  int s = c.x + c.y + c.z + c.w;
  int inc = s;
#pragma unroll
  for (int d = 1; d < 64; d <<= 1) {
    int u = __shfl_up(inc, d);
    if ((t & 63) >= d) inc += u;
  }
  __shared__ int wsum[4];
  if ((t & 63) == 63) wsum[t >> 6] = inc;
  __syncthreads();
  int add = 0;
  for (int w = 0; w < (t >> 6); ++w) add += wsum[w];
  int run = boff[bid] + inc + add - s;
  int vals[4] = {c.x, c.y, c.z, c.w};
#pragma unroll
  for (int j = 0; j < 4; ++j) {
    int idx = base + j;
    cursor8[idx] = run;
    if ((idx & 7) == 0) off[idx >> 3] = run;
    run += vals[j];
  }
  if (bid == 255 && t == 255) off[NSUB] = run;
}

__global__ __launch_bounds__(256) void edge_scatter8(const int* __restrict__ row,
                                                     const int* __restrict__ col,
                                                     const float* __restrict__ val,
                                                     int* __restrict__ cursor8,
                                                     int2* __restrict__ cv) {
  int i = blockIdx.x * 256 + threadIdx.x;
  int c = col[i];
  int p = atomicAdd(&cursor8[row[i] * 8 + (c >> 12)], 1);
  int2 e; e.x = c; e.y = __float_as_int(val[i]);
  cv[p] = e;
}

// ============ shared epilogue: bias+relu+mean/var-norm of one 512-col row ============
__device__ __forceinline__ void norm_rowstore(float* a, int lane, int r,
                                              const float* __restrict__ bias,
                                              const float* __restrict__ sc,
                                              const float* __restrict__ ofs,
                                              u16* __restrict__ Y, int ldy, int col_off) {
  float4 b0 = *(const float4*)(bias + lane * 8);
  float4 b1 = *(const float4*)(bias + lane * 8 + 4);
  a[0] = fmaxf(a[0] + b0.x, 0.f); a[1] = fmaxf(a[1] + b0.y, 0.f);
  a[2] = fmaxf(a[2] + b0.z, 0.f); a[3] = fmaxf(a[3] + b0.w, 0.f);
  a[4] = fmaxf(a[4] + b1.x, 0.f); a[5] = fmaxf(a[5] + b1.y, 0.f);
  a[6] = fmaxf(a[6] + b1.z, 0.f); a[7] = fmaxf(a[7] + b1.w, 0.f);
  float sum = 0.f, sq = 0.f;
#pragma unroll
  for (int j = 0; j < 8; ++j) { sum += a[j]; sq += a[j] * a[j]; }
#pragma unroll
  for (int d = 1; d < 64; d <<= 1) {
    sum += __shfl_xor(sum, d);
    sq  += __shfl_xor(sq, d);
  }
  float mean = sum * (1.f / 512.f);
  float var = sq * (1.f / 512.f) - mean * mean;
  float rstd = rsqrtf(var + 1e-9f);
  float4 s0 = *(const float4*)(sc + lane * 8);
  float4 s1 = *(const float4*)(sc + lane * 8 + 4);
  float4 o0 = *(const float4*)(ofs + lane * 8);
  float4 o1 = *(const float4*)(ofs + lane * 8 + 4);
  int4 o;
  o.x = (int)((u32)f2b((a[0] - mean) * s0.x * rstd + o0.x) |
              ((u32)f2b((a[1] - mean) * s0.y * rstd + o0.y) << 16));
  o.y = (int)((u32)f2b((a[2] - mean) * s0.z * rstd + o0.z) |
              ((u32)f2b((a[3] - mean) * s0.w * rstd + o0.w) << 16));
  o.z = (int)((u32)f2b((a[4] - mean) * s1.x * rstd + o1.x) |
              ((u32)f2b((a[5] - mean) * s1.y * rstd + o1.y) << 16));
  o.w = (int)((u32)f2b((a[6] - mean) * s1.z * rstd + o1.z) |
              ((u32)f2b((a[7] - mean) * s1.w * rstd + o1.w) << 16));
  *(int4*)(Y + (size_t)r * ldy + col_off + lane * 8) = o;
}

// ============ SpMM, one wave per row, 16B gathers, MLP=4 ============
__device__ __forceinline__ void fma8(int4 u, float v, float* a) {
  u32 w;
  w = (u32)u.x; a[0] += v * __uint_as_float(w << 16); a[1] += v * __uint_as_float(w & 0xffff0000u);
  w = (u32)u.y; a[2] += v * __uint_as_float(w << 16); a[3] += v * __uint_as_float(w & 0xffff0000u);
  w = (u32)u.z; a[4] += v * __uint_as_float(w << 16); a[5] += v * __uint_as_float(w & 0xffff0000u);
  w = (u32)u.w; a[6] += v * __uint_as_float(w << 16); a[7] += v * __uint_as_float(w & 0xffff0000u);
}

template <int LDX, bool NORM>
__device__ __forceinline__ void spmm_dev(const int* __restrict__ off,
                                         const int2* __restrict__ cv,
                                         const u16* __restrict__ X,
                                         u16* __restrict__ Y, int ldy, int col_off,
                                         const float* __restrict__ bias,
                                         const float* __restrict__ sc,
                                         const float* __restrict__ ofs, int bid) {
  const int lane = threadIdx.x & 63, wave = threadIdx.x >> 6;
  const int r = bid * 4 + wave;
  const int s = __builtin_amdgcn_readfirstlane(off[r]);
  const int e = __builtin_amdgcn_readfirstlane(off[r + 1]);
  float a[8] = {0.f, 0.f, 0.f, 0.f, 0.f, 0.f, 0.f, 0.f};
  const u16* Xl = X + lane * 8;
  int i = s;
  for (; i + 4 <= e; i += 4) {
    int2 p0 = cv[i], p1 = cv[i + 1], p2 = cv[i + 2], p3 = cv[i + 3];
    int4 u0 = *(const int4*)(Xl + (size_t)p0.x * LDX);
    int4 u1 = *(const int4*)(Xl + (size_t)p1.x * LDX);
    int4 u2 = *(const int4*)(Xl + (size_t)p2.x * LDX);
    int4 u3 = *(const int4*)(Xl + (size_t)p3.x * LDX);
    fma8(u0, __int_as_float(p0.y), a);
    fma8(u1, __int_as_float(p1.y), a);
    fma8(u2, __int_as_float(p2.y), a);
    fma8(u3, __int_as_float(p3.y), a);
  }
  for (; i < e; ++i) {
    int2 p0 = cv[i];
    int4 u0 = *(const int4*)(Xl + (size_t)p0.x * LDX);
    fma8(u0, __int_as_float(p0.y), a);
  }
  if (NORM) {
    norm_rowstore(a, lane, r, bias, sc, ofs, Y, ldy, col_off);
  } else {
    int4 o;
    o.x = (int)((u32)f2b(a[0]) | ((u32)f2b(a[1]) << 16));
    o.y = (int)((u32)f2b(a[2]) | ((u32)f2b(a[3]) << 16));
    o.z = (int)((u32)f2b(a[4]) | ((u32)f2b(a[5]) << 16));
    o.w = (int)((u32)f2b(a[6]) | ((u32)f2b(a[7]) << 16));
    *(int4*)(Y + (size_t)r * ldy + col_off + lane * 8) = o;
  }
}

// ============ wave-per-row rownorm (bf16 in) ============
__device__ __forceinline__ void rownorm_dev(const u16* __restrict__ F, int ldf,
                                            const float* __restrict__ bias,
                                            const float* __restrict__ sc,
                                            const float* __restrict__ ofs,
                                            u16* __restrict__ Y, int ldy, int col_off,
                                            int bid) {
  const int lane = threadIdx.x & 63, wave = threadIdx.x >> 6;
  const int r = bid * 4 + wave;
  int4 u = *(const int4*)(F + (size_t)r * ldf + lane * 8);
  float a[8];
  a[0] = __uint_as_float(((u32)u.x) << 16); a[1] = __uint_as_float(((u32)u.x) & 0xffff0000u);
  a[2] = __uint_as_float(((u32)u.y) << 16); a[3] = __uint_as_float(((u32)u.y) & 0xffff0000u);
  a[4] = __uint_as_float(((u32)u.z) << 16); a[5] = __uint_as_float(((u32)u.z) & 0xffff0000u);
  a[6] = __uint_as_float(((u32)u.w) << 16); a[7] = __uint_as_float(((u32)u.w) & 0xffff0000u);
  norm_rowstore(a, lane, r, bias, sc, ofs, Y, ldy, col_off);
}

__global__ __launch_bounds__(256) void rownorm_k(const u16* __restrict__ F, int ldf,
                                                 const float* __restrict__ bias,
                                                 const float* __restrict__ sc,
                                                 const float* __restrict__ ofs,
                                                 u16* __restrict__ Y, int col_off) {
  rownorm_dev(F, ldf, bias, sc, ofs, Y, 1024, col_off, blockIdx.x);
}

// ============ U_l1a: spmm1 ∥ gemm1-hop0 (verbatim gemm_bt body, nwg=1024, gx=4) ============
__global__ __launch_bounds__(256) void u_l1a(const int* __restrict__ row_off,
                                             const int2* __restrict__ cv,
                                             const u16* __restrict__ FEAT,
                                             u16* __restrict__ S1,
                                             const u16* __restrict__ W1_0b,
                                             u16* __restrict__ TMPa) {
  if (blockIdx.x >= 1024) {
    spmm_dev<512, false>(row_off, cv, FEAT, S1, 512, 0, nullptr, nullptr, nullptr,
                         blockIdx.x - 1024);
    return;
  }
  __shared__ __align__(16) u16 As[128 * 32];
  __shared__ __align__(16) u16 Bs[128 * 32];
  const int K = 512, LDC = 512;
  const int t = threadIdx.x;
  const int lane = t & 63, wave = t >> 6;
  const int wm = (wave >> 1) * 64, wn = (wave & 1) * 64;
  const int nwg = 1024;
  const int bid = blockIdx.x;
  const int sbid = (bid % 8) * (nwg / 8) + bid / 8;
  const int bx = sbid % 4, by = sbid / 4;
  const int m0 = by * 128, n0 = bx * 128;

  f32x4 acc[4][4];
#pragma unroll
  for (int m = 0; m < 4; ++m)
#pragma unroll
    for (int n = 0; n < 4; ++n) acc[m][n] = f32x4{0.f, 0.f, 0.f, 0.f};

  const int lr = t >> 2;
  const int lc = (t & 3) * 8;
  const u16* Ag  = FEAT + (size_t)(m0 + lr) * K + lc;
  const u16* Ag2 = Ag + (size_t)64 * K;
  const u16* Wg  = W1_0b + (size_t)(n0 + lr) * K + lc;
  const u16* Wg2 = Wg + (size_t)64 * K;
  char* asb0 = (char*)As + wave * 1024;
  char* asb1 = (char*)As + 4096 + wave * 1024;
  char* bsb0 = (char*)Bs + wave * 1024;
  char* bsb1 = (char*)Bs + 4096 + wave * 1024;
  const int fr = lane & 15, kh = lane >> 4;

  for (int kt = 0; kt < K / 32; ++kt) {
    glds16(Ag + kt * 32, asb0);
    glds16(Ag2 + kt * 32, asb1);
    glds16(Wg + kt * 32, bsb0);
    glds16(Wg2 + kt * 32, bsb1);
    __syncthreads();
    short8 af[4], bfr[4];
#pragma unroll
    for (int m = 0; m < 4; ++m)
      af[m] = *(const short8*)&As[(wm + m * 16 + fr) * 32 + kh * 8];
#pragma unroll
    for (int n = 0; n < 4; ++n)
      bfr[n] = *(const short8*)&Bs[(wn + n * 16 + fr) * 32 + kh * 8];
#pragma unroll
    for (int m = 0; m < 4; ++m)
#pragma unroll
      for (int n = 0; n < 4; ++n)
        acc[m][n] = __builtin_amdgcn_mfma_f32_16x16x32_bf16(af[m], bfr[n], acc[m][n], 0, 0, 0);
    __syncthreads();
  }

  const int crow = (lane >> 4) * 4;  // C/D: row=(lane>>4)*4+reg, col=lane&15
  const int ccol = lane & 15;
#pragma unroll
  for (int n = 0; n < 4; ++n) {
    int col = n0 + wn + n * 16 + ccol;
#pragma unroll
    for (int m = 0; m < 4; ++m) {
      int row = m0 + wm + m * 16 + crow;
#pragma unroll
      for (int q = 0; q < 4; ++q)
        TMPa[(size_t)(row + q) * LDC + col] = f2b(acc[m][n][q]);
    }
  }
}

// ============ U_l2: spmm2(+norm) ∥ rownorm2-hop0 ============
__global__ __launch_bounds__(256) void u_l2(const int* __restrict__ row_off,
                                            const int2* __restrict__ cv,
                                            const u16* __restrict__ TTL,
                                            u16* __restrict__ H2,
                                            const float* __restrict__ b2_0,
                                            const float* __restrict__ s2_0,
                                            const float* __restrict__ o2_0,
                                            const float* __restrict__ b2_1,
                                            const float* __restrict__ s2_1,
                                            const float* __restrict__ o2_1) {
  int bid = blockIdx.x;
  if (bid < 8192)
    spmm_dev<1024, true>(row_off, cv, TTL + 512, H2, 1024, 512, b2_1, s2_1, o2_1, bid);
  else
    rownorm_dev(TTL, 1024, b2_0, s2_0, o2_0, H2, 1024, 0, bid - 8192);
}

// ============ bf16 MFMA GEMM: C[M,N] = A[M,K] @ W[N,K]^T ============
// 128x128 tile, glds staging, XCD swizzle. RS: scale acc by rs[row] (L2-norm fold).
template <int K, int LDC, bool BIAS, bool BF16OUT, bool RS>
__global__ __launch_bounds__(256) void gemm_bt(const u16* __restrict__ A,
                                               const u16* __restrict__ W,
                                               const float* __restrict__ bias,
                                               const float* __restrict__ rs,
                                               float* __restrict__ Cf,
                                               u16* __restrict__ Cb) {
  __shared__ __align__(16) u16 As[128 * 32];
  __shared__ __align__(16) u16 Bs[128 * 32];
  const int t = threadIdx.x;
  const int lane = t & 63, wave = t >> 6;
  const int wm = (wave >> 1) * 64, wn = (wave & 1) * 64;
  const int nwg = gridDim.x * gridDim.y;
  const int bid = blockIdx.x + gridDim.x * blockIdx.y;
  const int sbid = (bid % 8) * (nwg / 8) + bid / 8;
  const int bx = sbid % gridDim.x, by = sbid / gridDim.x;
  const int m0 = by * 128, n0 = bx * 128;

  f32x4 acc[4][4];
#pragma unroll
  for (int m = 0; m < 4; ++m)
#pragma unroll
    for (int n = 0; n < 4; ++n) acc[m][n] = f32x4{0.f, 0.f, 0.f, 0.f};

  const int lr = t >> 2;
  const int lc = (t & 3) * 8;
  const u16* Ag  = A + (size_t)(m0 + lr) * K + lc;
  const u16* Ag2 = Ag + (size_t)64 * K;
  const u16* Wg  = W + (size_t)(n0 + lr) * K + lc;
  const u16* Wg2 = Wg + (size_t)64 * K;
  char* asb0 = (char*)As + wave * 1024;
  char* asb1 = (char*)As + 4096 + wave * 1024;
  char* bsb0 = (char*)Bs + wave * 1024;
  char* bsb1 = (char*)Bs + 4096 + wave * 1024;
  const int fr = lane & 15, kh = lane >> 4;

  for (int kt = 0; kt < K / 32; ++kt) {
    glds16(Ag + kt * 32, asb0);
    glds16(Ag2 + kt * 32, asb1);
    glds16(Wg + kt * 32, bsb0);
    glds16(Wg2 + kt * 32, bsb1);
    __syncthreads();
    short8 af[4], bfr[4];
#pragma unroll
    for (int m = 0; m < 4; ++m)
      af[m] = *(const short8*)&As[(wm + m * 16 + fr) * 32 + kh * 8];
#pragma unroll
    for (int n = 0; n < 4; ++n)
      bfr[n] = *(const short8*)&Bs[(wn + n * 16 + fr) * 32 + kh * 8];
#pragma unroll
    for (int m = 0; m < 4; ++m)
#pragma unroll
      for (int n = 0; n < 4; ++n)
        acc[m][n] = __builtin_amdgcn_mfma_f32_16x16x32_bf16(af[m], bfr[n], acc[m][n], 0, 0, 0);
    __syncthreads();
  }

  const int crow = (lane >> 4) * 4;  // C/D: row=(lane>>4)*4+reg, col=lane&15
  const int ccol = lane & 15;
#pragma unroll
  for (int n = 0; n < 4; ++n) {
    int col = n0 + wn + n * 16 + ccol;
    float bv = BIAS ? bias[col] : 0.f;
#pragma unroll
    for (int m = 0; m < 4; ++m) {
      int row = m0 + wm + m * 16 + crow;
#pragma unroll
      for (int q = 0; q < 4; ++q) {
        float v = acc[m][n][q];
        if (RS) v *= rs[row + q];
        v += bv;
        if (BF16OUT)
          Cb[(size_t)(row + q) * LDC + col] = f2b(v);
        else
          Cf[(size_t)(row + q) * LDC + col] = v;
      }
    }
  }
}

// ============ per-row 1/L2-norm of bf16 [NSUB,1024] ============
__global__ __launch_bounds__(256) void l2scale(const u16* __restrict__ H,
                                               float* __restrict__ rn) {
  const int lane = threadIdx.x & 63, wave = threadIdx.x >> 6;
  const int r = blockIdx.x * 4 + wave;
  const u16* row = H + (size_t)r * 1024 + lane * 16;
  int4 u0 = *(const int4*)row;
  int4 u1 = *(const int4*)(row + 8);
  float sq = 0.f;
  const int vals[8] = {u0.x, u0.y, u0.z, u0.w, u1.x, u1.y, u1.z, u1.w};
#pragma unroll
  for (int j = 0; j < 8; ++j) {
    u32 wv = (u32)vals[j];
    float f0 = __uint_as_float(wv << 16);
    float f1 = __uint_as_float(wv & 0xffff0000u);
    sq += f0 * f0 + f1 * f1;
  }
#pragma unroll
  for (int d = 1; d < 64; d <<= 1) sq += __shfl_xor(sq, d);
  if (lane == 0) rn[r] = 1.f / fmaxf(sqrtf(sq), 1e-12f);
}

extern "C" void kernel_launch(void* const* d_in, const int* in_sizes, int n_in,
                              void* d_out, int out_size, void* d_ws, size_t ws_size,
                              hipStream_t stream) {
  (void)in_sizes; (void)n_in; (void)out_size; (void)ws_size;
  const float* feat_full = (const float*)d_in[0];
  const int*   nodes = (const int*)d_in[1];
  const int*   arow = (const int*)d_in[2];
  const int*   acol = (const int*)d_in[3];
  const float* aval = (const float*)d_in[4];
  const float* W1_0 = (const float*)d_in[5];
  const float* W1_1 = (const float*)d_in[6];
  const float* b1_0 = (const float*)d_in[7];
  const float* b1_1 = (const float*)d_in[8];
  const float* s1_0 = (const float*)d_in[9];
  const float* s1_1 = (const float*)d_in[10];
  const float* o1_0 = (const float*)d_in[11];
  const float* o1_1 = (const float*)d_in[12];
  const float* W2_0 = (const float*)d_in[13];
  const float* W2_1 = (const float*)d_in[14];
  const float* b2_0 = (const float*)d_in[15];
  const float* b2_1 = (const float*)d_in[16];
  const float* s2_0 = (const float*)d_in[17];
  const float* s2_1 = (const float*)d_in[18];
  const float* o2_0 = (const float*)d_in[19];
  const float* o2_1 = (const float*)d_in[20];
  const float* Wc = (const float*)d_in[21];
  const float* bc = (const float*)d_in[22];
  float* out = (float*)d_out;

  const size_t MB = (size_t)1 << 20;
  char* p = (char*)d_ws;
  u16* FEAT = (u16*)p;                    // 32 MiB [NSUB,512]
  u16* S1   = (u16*)(p + 32 * MB);        // 32 MiB
  u16* H1   = (u16*)(p + 64 * MB);        // 64 MiB [NSUB,1024]
  u16* H2   = (u16*)(p + 128 * MB);       // 64 MiB
  u16* TMPa = (u16*)(p + 192 * MB);       // 32 MiB hop0 preact
  u16* TMPb = (u16*)(p + 224 * MB);       // 32 MiB hop1 preact
  u16* TTL  = (u16*)(p + 192 * MB);       // 64 MiB layer-2 preact (reuses TMPa/b)
  u16* W1_0b = (u16*)(p + 256 * MB);
  u16* W1_1b = W1_0b + 512 * 512;
  u16* W2cat = W1_1b + 512 * 512;         // [1024,1024]
  u16* Wcb   = W2cat + 1024 * 1024;
  int* row_off = (int*)(p + 260 * MB);
  int* cnt8    = (int*)(p + 261 * MB);
  int* cursor8 = (int*)(p + 262 * MB);
  float* RN    = (float*)(p + 263 * MB);
  int* bsum    = (int*)((char*)RN + 256 * 1024);
  int* boff    = bsum + 256;
  int2* cv     = (int2*)(p + 264 * MB);

  hipMemsetAsync(cnt8, 0, NSUB * 8 * sizeof(int), stream);

  // prep: gather ∥ edge-count ∥ weight casts
  u_prep<<<GATHER_B + COUNT_B + 2048, 256, 0, stream>>>(
      feat_full, nodes, FEAT, arow, acol, cnt8,
      W1_0, W1_1, W2_0, W2_1, Wc, W1_0b, W1_1b, W2cat, Wcb);

  scan_part<<<256, 256, 0, stream>>>(cnt8, bsum);
  scan_top<<<1, 256, 0, stream>>>(bsum, boff);
  scan_final<<<256, 256, 0, stream>>>(cnt8, boff, row_off, cursor8);
  edge_scatter8<<<NNZ_E / 256, 256, 0, stream>>>(arow, acol, aval, cursor8, cv);

  // ---- layer 1: union {gemm1-hop0 ∥ spmm1}, then hop1 gemm + rownorms ----
  u_l1a<<<1024 + 8192, 256, 0, stream>>>(row_off, cv, FEAT, S1, W1_0b, TMPa);
  gemm_bt<512, 512, false, true, false><<<dim3(4, 256), 256, 0, stream>>>(
      S1, W1_1b, nullptr, nullptr, nullptr, TMPb);
  rownorm_k<<<NSUB / 4, 256, 0, stream>>>(TMPa, 512, b1_0, s1_0, o1_0, H1, 0);
  rownorm_k<<<NSUB / 4, 256, 0, stream>>>(TMPb, 512, b1_1, s1_1, o1_1, H1, 512);

  // ---- layer 2 (merged GEMM -> TTL; union spmm2+norm ∥ rownorm2-hop0) ----
  gemm_bt<1024, 1024, false, true, false><<<dim3(8, 256), 256, 0, stream>>>(
      H1, W2cat, nullptr, nullptr, nullptr, TTL);
  u_l2<<<8192 + 8192, 256, 0, stream>>>(row_off, cv, TTL, H2,
                                        b2_0, s2_0, o2_0, b2_1, s2_1, o2_1);

  // ---- classifier with folded L2 normalization ----
  l2scale<<<NSUB / 4, 256, 0, stream>>>(H2, RN);
  gemm_bt<1024, 512, true, false, true><<<dim3(4, 256), 256, 0, stream>>>(
      H2, Wcb, bc, RN, out, nullptr);
}

// Round 13
// 633.529 us; speedup vs baseline: 1.4114x; 1.0088x over previous
//
#include <hip/hip_runtime.h>
#include <stdint.h>

typedef unsigned short u16;
typedef unsigned int u32;

#define NSUB 32768
#define NNZ_E 1048576

using short8 = __attribute__((ext_vector_type(8))) short;
using f32x4  = __attribute__((ext_vector_type(4))) float;

__device__ __forceinline__ u16 f2b(float f) {
  u32 u = __float_as_uint(f);
  return (u16)((u + 0x7fffu + ((u >> 16) & 1u)) >> 16);
}
__device__ __forceinline__ float b2f(u16 x) {
  return __uint_as_float(((u32)x) << 16);
}

__device__ __forceinline__ void glds16(const void* g, void* l) {
  __builtin_amdgcn_global_load_lds(
      (const __attribute__((address_space(1))) u32*)g,
      (__attribute__((address_space(3))) u32*)l, 16, 0, 0);
}

// ============ U_prep: gather ∥ edge-count ∥ 5x weight-cast ============
#define GATHER_B 16384
#define COUNT_B 4096
__global__ __launch_bounds__(256) void u_prep(
    const float* __restrict__ ff, const int* __restrict__ idx, u16* __restrict__ FEAT,
    const int* __restrict__ arow, const int* __restrict__ acol, int* __restrict__ cnt8,
    const float* W1_0, const float* W1_1, const float* W2_0, const float* W2_1,
    const float* Wc, u16* W1_0b, u16* W1_1b, u16* W2cat, u16* Wcb) {
  int bid = blockIdx.x, t = threadIdx.x;
  if (bid < GATHER_B) {
    int r = bid * 2 + (t >> 7);
    int c = (t & 127) * 4;
    size_t src = (size_t)idx[r];
    float4 v = *(const float4*)(ff + src * 512 + c);
    ushort4 o;
    o.x = f2b(v.x); o.y = f2b(v.y); o.z = f2b(v.z); o.w = f2b(v.w);
    *(ushort4*)(FEAT + (size_t)r * 512 + c) = o;
  } else if (bid < GATHER_B + COUNT_B) {
    int i = (bid - GATHER_B) * 256 + t;
    atomicAdd(&cnt8[arow[i] * 8 + (acol[i] >> 12)], 1);
  } else {
    int cid = bid - GATHER_B - COUNT_B;
    const float* src; u16* dst; int i;
    if (cid < 256)       { src = W1_0; dst = W1_0b;              i = cid * 256 + t; }
    else if (cid < 512)  { src = W1_1; dst = W1_1b;              i = (cid - 256) * 256 + t; }
    else if (cid < 1024) { src = W2_0; dst = W2cat;              i = (cid - 512) * 256 + t; }
    else if (cid < 1536) { src = W2_1; dst = W2cat + 512 * 1024; i = (cid - 1024) * 256 + t; }
    else                 { src = Wc;   dst = Wcb;                i = (cid - 1536) * 256 + t; }
    float4 v = ((const float4*)src)[i];
    ushort4 o;
    o.x = f2b(v.x); o.y = f2b(v.y); o.z = f2b(v.z); o.w = f2b(v.w);
    ((ushort4*)dst)[i] = o;
  }
}

// ============ hierarchical scan of cnt8[262144] ============
__global__ __launch_bounds__(256) void scan_part(const int* __restrict__ cnt8,
                                                 int* __restrict__ bsum) {
  int bid = blockIdx.x, t = threadIdx.x;
  int4 c = *(const int4*)(cnt8 + bid * 1024 + t * 4);
  int s = c.x + c.y + c.z + c.w;
#pragma unroll
  for (int d = 1; d < 64; d <<= 1) s += __shfl_xor(s, d);
  __shared__ int red[4];
  if ((t & 63) == 0) red[t >> 6] = s;
  __syncthreads();
  if (t == 0) bsum[bid] = red[0] + red[1] + red[2] + red[3];
}

__global__ __launch_bounds__(256) void scan_top(const int* __restrict__ bsum,
                                                int* __restrict__ boff) {
  int t = threadIdx.x;
  int v = bsum[t];
  int s = v;
#pragma unroll
  for (int d = 1; d < 64; d <<= 1) {
    int u = __shfl_up(s, d);
    if ((t & 63) >= d) s += u;
  }
  __shared__ int wsum[4];
  if ((t & 63) == 63) wsum[t >> 6] = s;
  __syncthreads();
  int add = 0;
  for (int w = 0; w < (t >> 6); ++w) add += wsum[w];
  boff[t] = s + add - v;  // exclusive
}

__global__ __launch_bounds__(256) void scan_final(const int* __restrict__ cnt8,
                                                  const int* __restrict__ boff,
                                                  int* __restrict__ off,
                                                  int* __restrict__ cursor8) {
  int bid = blockIdx.x, t = threadIdx.x;
  int base = bid * 1024 + t * 4;
  int4 c = *(const int4*)(cnt8 + base);
  int s = c.x + c.y + c.z + c.w;
  int inc = s;
#pragma unroll
  for (int d = 1; d < 64; d <<= 1) {
    int u = __shfl_up(inc, d);
    if ((t & 63) >= d) inc += u;
  }
  __shared__ int wsum[4];
  if ((t & 63) == 63) wsum[t >> 6] = inc;
  __syncthreads();
  int add = 0;
  for (int w = 0; w < (t >> 6); ++w) add += wsum[w];
  int run = boff[bid] + inc + add - s;
  int vals[4] = {c.x, c.y, c.z, c.w};
#pragma unroll
  for (int j = 0; j < 4; ++j) {
    int idx = base + j;
    cursor8[idx] = run;
    if ((idx & 7) == 0) off[idx >> 3] = run;
    run += vals[j];
  }
  if (bid == 255 && t == 255) off[NSUB] = run;
}

__global__ __launch_bounds__(256) void edge_scatter8(const int* __restrict__ row,
                                                     const int* __restrict__ col,
                                                     const float* __restrict__ val,
                                                     int* __restrict__ cursor8,
                                                     int2* __restrict__ cv) {
  int i = blockIdx.x * 256 + threadIdx.x;
  int c = col[i];
  int p = atomicAdd(&cursor8[row[i] * 8 + (c >> 12)], 1);
  int2 e; e.x = c; e.y = __float_as_int(val[i]);
  cv[p] = e;
}

// ============ shared epilogue: bias+relu+mean/var-norm of one 512-col row ============
__device__ __forceinline__ void norm_rowstore(float* a, int lane, int r,
                                              const float* __restrict__ bias,
                                              const float* __restrict__ sc,
                                              const float* __restrict__ ofs,
                                              u16* __restrict__ Y, int ldy, int col_off) {
  float4 b0 = *(const float4*)(bias + lane * 8);
  float4 b1 = *(const float4*)(bias + lane * 8 + 4);
  a[0] = fmaxf(a[0] + b0.x, 0.f); a[1] = fmaxf(a[1] + b0.y, 0.f);
  a[2] = fmaxf(a[2] + b0.z, 0.f); a[3] = fmaxf(a[3] + b0.w, 0.f);
  a[4] = fmaxf(a[4] + b1.x, 0.f); a[5] = fmaxf(a[5] + b1.y, 0.f);
  a[6] = fmaxf(a[6] + b1.z, 0.f); a[7] = fmaxf(a[7] + b1.w, 0.f);
  float sum = 0.f, sq = 0.f;
#pragma unroll
  for (int j = 0; j < 8; ++j) { sum += a[j]; sq += a[j] * a[j]; }
#pragma unroll
  for (int d = 1; d < 64; d <<= 1) {
    sum += __shfl_xor(sum, d);
    sq  += __shfl_xor(sq, d);
  }
  float mean = sum * (1.f / 512.f);
  float var = sq * (1.f / 512.f) - mean * mean;
  float rstd = rsqrtf(var + 1e-9f);
  float4 s0 = *(const float4*)(sc + lane * 8);
  float4 s1 = *(const float4*)(sc + lane * 8 + 4);
  float4 o0 = *(const float4*)(ofs + lane * 8);
  float4 o1 = *(const float4*)(ofs + lane * 8 + 4);
  int4 o;
  o.x = (int)((u32)f2b((a[0] - mean) * s0.x * rstd + o0.x) |
              ((u32)f2b((a[1] - mean) * s0.y * rstd + o0.y) << 16));
  o.y = (int)((u32)f2b((a[2] - mean) * s0.z * rstd + o0.z) |
              ((u32)f2b((a[3] - mean) * s0.w * rstd + o0.w) << 16));
  o.z = (int)((u32)f2b((a[4] - mean) * s1.x * rstd + o1.x) |
              ((u32)f2b((a[5] - mean) * s1.y * rstd + o1.y) << 16));
  o.w = (int)((u32)f2b((a[6] - mean) * s1.z * rstd + o1.z) |
              ((u32)f2b((a[7] - mean) * s1.w * rstd + o1.w) << 16));
  *(int4*)(Y + (size_t)r * ldy + col_off + lane * 8) = o;
}

// ============ SpMM, one wave per row, 16B gathers, MLP=4 ============
__device__ __forceinline__ void fma8(int4 u, float v, float* a) {
  u32 w;
  w = (u32)u.x; a[0] += v * __uint_as_float(w << 16); a[1] += v * __uint_as_float(w & 0xffff0000u);
  w = (u32)u.y; a[2] += v * __uint_as_float(w << 16); a[3] += v * __uint_as_float(w & 0xffff0000u);
  w = (u32)u.z; a[4] += v * __uint_as_float(w << 16); a[5] += v * __uint_as_float(w & 0xffff0000u);
  w = (u32)u.w; a[6] += v * __uint_as_float(w << 16); a[7] += v * __uint_as_float(w & 0xffff0000u);
}

template <int LDX, bool NORM>
__device__ __forceinline__ void spmm_dev(const int* __restrict__ off,
                                         const int2* __restrict__ cv,
                                         const u16* __restrict__ X,
                                         u16* __restrict__ Y, int ldy, int col_off,
                                         const float* __restrict__ bias,
                                         const float* __restrict__ sc,
                                         const float* __restrict__ ofs, int bid) {
  const int lane = threadIdx.x & 63, wave = threadIdx.x >> 6;
  const int r = bid * 4 + wave;
  const int s = __builtin_amdgcn_readfirstlane(off[r]);
  const int e = __builtin_amdgcn_readfirstlane(off[r + 1]);
  float a[8] = {0.f, 0.f, 0.f, 0.f, 0.f, 0.f, 0.f, 0.f};
  const u16* Xl = X + lane * 8;
  int i = s;
  for (; i + 4 <= e; i += 4) {
    int2 p0 = cv[i], p1 = cv[i + 1], p2 = cv[i + 2], p3 = cv[i + 3];
    int4 u0 = *(const int4*)(Xl + (size_t)p0.x * LDX);
    int4 u1 = *(const int4*)(Xl + (size_t)p1.x * LDX);
    int4 u2 = *(const int4*)(Xl + (size_t)p2.x * LDX);
    int4 u3 = *(const int4*)(Xl + (size_t)p3.x * LDX);
    fma8(u0, __int_as_float(p0.y), a);
    fma8(u1, __int_as_float(p1.y), a);
    fma8(u2, __int_as_float(p2.y), a);
    fma8(u3, __int_as_float(p3.y), a);
  }
  for (; i < e; ++i) {
    int2 p0 = cv[i];
    int4 u0 = *(const int4*)(Xl + (size_t)p0.x * LDX);
    fma8(u0, __int_as_float(p0.y), a);
  }
  if (NORM) {
    norm_rowstore(a, lane, r, bias, sc, ofs, Y, ldy, col_off);
  } else {
    int4 o;
    o.x = (int)((u32)f2b(a[0]) | ((u32)f2b(a[1]) << 16));
    o.y = (int)((u32)f2b(a[2]) | ((u32)f2b(a[3]) << 16));
    o.z = (int)((u32)f2b(a[4]) | ((u32)f2b(a[5]) << 16));
    o.w = (int)((u32)f2b(a[6]) | ((u32)f2b(a[7]) << 16));
    *(int4*)(Y + (size_t)r * ldy + col_off + lane * 8) = o;
  }
}

// ============ wave-per-row rownorm (bf16 in) ============
__device__ __forceinline__ void rownorm_dev(const u16* __restrict__ F, int ldf,
                                            const float* __restrict__ bias,
                                            const float* __restrict__ sc,
                                            const float* __restrict__ ofs,
                                            u16* __restrict__ Y, int ldy, int col_off,
                                            int bid) {
  const int lane = threadIdx.x & 63, wave = threadIdx.x >> 6;
  const int r = bid * 4 + wave;
  int4 u = *(const int4*)(F + (size_t)r * ldf + lane * 8);
  float a[8];
  a[0] = __uint_as_float(((u32)u.x) << 16); a[1] = __uint_as_float(((u32)u.x) & 0xffff0000u);
  a[2] = __uint_as_float(((u32)u.y) << 16); a[3] = __uint_as_float(((u32)u.y) & 0xffff0000u);
  a[4] = __uint_as_float(((u32)u.z) << 16); a[5] = __uint_as_float(((u32)u.z) & 0xffff0000u);
  a[6] = __uint_as_float(((u32)u.w) << 16); a[7] = __uint_as_float(((u32)u.w) & 0xffff0000u);
  norm_rowstore(a, lane, r, bias, sc, ofs, Y, ldy, col_off);
}

__global__ __launch_bounds__(256) void rownorm_k(const u16* __restrict__ F, int ldf,
                                                 const float* __restrict__ bias,
                                                 const float* __restrict__ sc,
                                                 const float* __restrict__ ofs,
                                                 u16* __restrict__ Y, int col_off) {
  rownorm_dev(F, ldf, bias, sc, ofs, Y, 1024, col_off, blockIdx.x);
}

// ============ U_l1a: spmm1 ∥ gemm1-hop0 (verbatim inline gemm, nwg=1024, gx=4) ============
__global__ __launch_bounds__(256) void u_l1a(const int* __restrict__ row_off,
                                             const int2* __restrict__ cv,
                                             const u16* __restrict__ FEAT,
                                             u16* __restrict__ S1,
                                             const u16* __restrict__ W1_0b,
                                             u16* __restrict__ TMPa) {
  if (blockIdx.x >= 1024) {
    spmm_dev<512, false>(row_off, cv, FEAT, S1, 512, 0, nullptr, nullptr, nullptr,
                         blockIdx.x - 1024);
    return;
  }
  __shared__ __align__(16) u16 As[128 * 32];
  __shared__ __align__(16) u16 Bs[128 * 32];
  const int K = 512, LDC = 512;
  const int t = threadIdx.x;
  const int lane = t & 63, wave = t >> 6;
  const int wm = (wave >> 1) * 64, wn = (wave & 1) * 64;
  const int nwg = 1024;
  const int bid = blockIdx.x;
  const int sbid = (bid % 8) * (nwg / 8) + bid / 8;
  const int bx = sbid % 4, by = sbid / 4;
  const int m0 = by * 128, n0 = bx * 128;

  f32x4 acc[4][4];
#pragma unroll
  for (int m = 0; m < 4; ++m)
#pragma unroll
    for (int n = 0; n < 4; ++n) acc[m][n] = f32x4{0.f, 0.f, 0.f, 0.f};

  const int lr = t >> 2;
  const int lc = (t & 3) * 8;
  const u16* Ag  = FEAT + (size_t)(m0 + lr) * K + lc;
  const u16* Ag2 = Ag + (size_t)64 * K;
  const u16* Wg  = W1_0b + (size_t)(n0 + lr) * K + lc;
  const u16* Wg2 = Wg + (size_t)64 * K;
  char* asb0 = (char*)As + wave * 1024;
  char* asb1 = (char*)As + 4096 + wave * 1024;
  char* bsb0 = (char*)Bs + wave * 1024;
  char* bsb1 = (char*)Bs + 4096 + wave * 1024;
  const int fr = lane & 15, kh = lane >> 4;

  for (int kt = 0; kt < K / 32; ++kt) {
    glds16(Ag + kt * 32, asb0);
    glds16(Ag2 + kt * 32, asb1);
    glds16(Wg + kt * 32, bsb0);
    glds16(Wg2 + kt * 32, bsb1);
    __syncthreads();
    short8 af[4], bfr[4];
#pragma unroll
    for (int m = 0; m < 4; ++m)
      af[m] = *(const short8*)&As[(wm + m * 16 + fr) * 32 + kh * 8];
#pragma unroll
    for (int n = 0; n < 4; ++n)
      bfr[n] = *(const short8*)&Bs[(wn + n * 16 + fr) * 32 + kh * 8];
#pragma unroll
    for (int m = 0; m < 4; ++m)
#pragma unroll
      for (int n = 0; n < 4; ++n)
        acc[m][n] = __builtin_amdgcn_mfma_f32_16x16x32_bf16(af[m], bfr[n], acc[m][n], 0, 0, 0);
    __syncthreads();
  }

  const int crow = (lane >> 4) * 4;  // C/D: row=(lane>>4)*4+reg, col=lane&15
  const int ccol = lane & 15;
#pragma unroll
  for (int n = 0; n < 4; ++n) {
    int col = n0 + wn + n * 16 + ccol;
#pragma unroll
    for (int m = 0; m < 4; ++m) {
      int row = m0 + wm + m * 16 + crow;
#pragma unroll
      for (int q = 0; q < 4; ++q)
        TMPa[(size_t)(row + q) * LDC + col] = f2b(acc[m][n][q]);
    }
  }
}

// ============ U_l2: spmm2(+norm) ∥ rownorm2-hop0 ============
__global__ __launch_bounds__(256) void u_l2(const int* __restrict__ row_off,
                                            const int2* __restrict__ cv,
                                            const u16* __restrict__ TTL,
                                            u16* __restrict__ H2,
                                            const float* __restrict__ b2_0,
                                            const float* __restrict__ s2_0,
                                            const float* __restrict__ o2_0,
                                            const float* __restrict__ b2_1,
                                            const float* __restrict__ s2_1,
                                            const float* __restrict__ o2_1) {
  int bid = blockIdx.x;
  if (bid < 8192)
    spmm_dev<1024, true>(row_off, cv, TTL + 512, H2, 1024, 512, b2_1, s2_1, o2_1, bid);
  else
    rownorm_dev(TTL, 1024, b2_0, s2_0, o2_0, H2, 1024, 0, bid - 8192);
}

// ============ bf16 MFMA GEMM, BK=32 (proven path) ============
template <int K, int LDC, bool BIAS, bool BF16OUT, bool RS>
__global__ __launch_bounds__(256) void gemm_bt(const u16* __restrict__ A,
                                               const u16* __restrict__ W,
                                               const float* __restrict__ bias,
                                               const float* __restrict__ rs,
                                               float* __restrict__ Cf,
                                               u16* __restrict__ Cb) {
  __shared__ __align__(16) u16 As[128 * 32];
  __shared__ __align__(16) u16 Bs[128 * 32];
  const int t = threadIdx.x;
  const int lane = t & 63, wave = t >> 6;
  const int wm = (wave >> 1) * 64, wn = (wave & 1) * 64;
  const int nwg = gridDim.x * gridDim.y;
  const int bid = blockIdx.x + gridDim.x * blockIdx.y;
  const int sbid = (bid % 8) * (nwg / 8) + bid / 8;
  const int bx = sbid % gridDim.x, by = sbid / gridDim.x;
  const int m0 = by * 128, n0 = bx * 128;

  f32x4 acc[4][4];
#pragma unroll
  for (int m = 0; m < 4; ++m)
#pragma unroll
    for (int n = 0; n < 4; ++n) acc[m][n] = f32x4{0.f, 0.f, 0.f, 0.f};

  const int lr = t >> 2;
  const int lc = (t & 3) * 8;
  const u16* Ag  = A + (size_t)(m0 + lr) * K + lc;
  const u16* Ag2 = Ag + (size_t)64 * K;
  const u16* Wg  = W + (size_t)(n0 + lr) * K + lc;
  const u16* Wg2 = Wg + (size_t)64 * K;
  char* asb0 = (char*)As + wave * 1024;
  char* asb1 = (char*)As + 4096 + wave * 1024;
  char* bsb0 = (char*)Bs + wave * 1024;
  char* bsb1 = (char*)Bs + 4096 + wave * 1024;
  const int fr = lane & 15, kh = lane >> 4;

  for (int kt = 0; kt < K / 32; ++kt) {
    glds16(Ag + kt * 32, asb0);
    glds16(Ag2 + kt * 32, asb1);
    glds16(Wg + kt * 32, bsb0);
    glds16(Wg2 + kt * 32, bsb1);
    __syncthreads();
    short8 af[4], bfr[4];
#pragma unroll
    for (int m = 0; m < 4; ++m)
      af[m] = *(const short8*)&As[(wm + m * 16 + fr) * 32 + kh * 8];
#pragma unroll
    for (int n = 0; n < 4; ++n)
      bfr[n] = *(const short8*)&Bs[(wn + n * 16 + fr) * 32 + kh * 8];
#pragma unroll
    for (int m = 0; m < 4; ++m)
#pragma unroll
      for (int n = 0; n < 4; ++n)
        acc[m][n] = __builtin_amdgcn_mfma_f32_16x16x32_bf16(af[m], bfr[n], acc[m][n], 0, 0, 0);
    __syncthreads();
  }

  const int crow = (lane >> 4) * 4;
  const int ccol = lane & 15;
#pragma unroll
  for (int n = 0; n < 4; ++n) {
    int col = n0 + wn + n * 16 + ccol;
    float bv = BIAS ? bias[col] : 0.f;
#pragma unroll
    for (int m = 0; m < 4; ++m) {
      int row = m0 + wm + m * 16 + crow;
#pragma unroll
      for (int q = 0; q < 4; ++q) {
        float v = acc[m][n][q];
        if (RS) v *= rs[row + q];
        v += bv;
        if (BF16OUT)
          Cb[(size_t)(row + q) * LDC + col] = f2b(v);
        else
          Cf[(size_t)(row + q) * LDC + col] = v;
      }
    }
  }
}

// ============ bf16 MFMA GEMM, BK=64 + source-side XOR swizzle (merged layer-2) ============
// LDS rows are 128B (64 u16): slot s (16B) of row r stores global slot s^(r&7).
// Staged via glds16 with pre-swizzled per-lane GLOBAL address (LDS stays linear);
// reads apply the same XOR -> conflict-free ds_read_b128.
template <int K, int LDC>
__global__ __launch_bounds__(256) void gemm64_bt(const u16* __restrict__ A,
                                                 const u16* __restrict__ W,
                                                 u16* __restrict__ Cb) {
  __shared__ __align__(16) u16 As[128 * 64];
  __shared__ __align__(16) u16 Bs[128 * 64];
  const int t = threadIdx.x;
  const int lane = t & 63, wave = t >> 6;
  const int wm = (wave >> 1) * 64, wn = (wave & 1) * 64;
  const int nwg = gridDim.x * gridDim.y;
  const int bid = blockIdx.x + gridDim.x * blockIdx.y;
  const int sbid = (bid % 8) * (nwg / 8) + bid / 8;
  const int bx = sbid % gridDim.x, by = sbid / gridDim.x;
  const int m0 = by * 128, n0 = bx * 128;

  f32x4 acc[4][4];
#pragma unroll
  for (int m = 0; m < 4; ++m)
#pragma unroll
    for (int n = 0; n < 4; ++n) acc[m][n] = f32x4{0.f, 0.f, 0.f, 0.f};

  // staging: chunk c covers rows c*32..+32; thread t -> row c*32+(t>>3), LDS slot t&7;
  // global source slot = (t&7) ^ ((t>>3)&7)  [row&7 == (t>>3)&7]
  const int sr = t >> 3;
  const int ss = (t & 7) ^ (sr & 7);
  const u16* Asrc = A + (size_t)(m0 + sr) * K + ss * 8;
  const u16* Bsrc = W + (size_t)(n0 + sr) * K + ss * 8;
  char* adst = (char*)As + wave * 1024;
  char* bdst = (char*)Bs + wave * 1024;
  const int fr = lane & 15, kh = lane >> 4;
  const int sw = fr & 7;  // read-side XOR (row&7 == fr&7 since wm, m*16 are mult. of 8)

  for (int kt = 0; kt < K / 64; ++kt) {
#pragma unroll
    for (int c = 0; c < 4; ++c) {
      glds16(Asrc + (size_t)(c * 32) * K + kt * 64, adst + c * 4096);
      glds16(Bsrc + (size_t)(c * 32) * K + kt * 64, bdst + c * 4096);
    }
    __syncthreads();
#pragma unroll
    for (int kk = 0; kk < 2; ++kk) {
      const int so = ((kk * 4 + kh) ^ sw) * 8;
      short8 af[4], bfr[4];
#pragma unroll
      for (int m = 0; m < 4; ++m)
        af[m] = *(const short8*)&As[(wm + m * 16 + fr) * 64 + so];
#pragma unroll
      for (int n = 0; n < 4; ++n)
        bfr[n] = *(const short8*)&Bs[(wn + n * 16 + fr) * 64 + so];
#pragma unroll
      for (int m = 0; m < 4; ++m)
#pragma unroll
        for (int n = 0; n < 4; ++n)
          acc[m][n] = __builtin_amdgcn_mfma_f32_16x16x32_bf16(af[m], bfr[n], acc[m][n], 0, 0, 0);
    }
    __syncthreads();
  }

  const int crow = (lane >> 4) * 4;
  const int ccol = lane & 15;
#pragma unroll
  for (int n = 0; n < 4; ++n) {
    int col = n0 + wn + n * 16 + ccol;
#pragma unroll
    for (int m = 0; m < 4; ++m) {
      int row = m0 + wm + m * 16 + crow;
#pragma unroll
      for (int q = 0; q < 4; ++q)
        Cb[(size_t)(row + q) * LDC + col] = f2b(acc[m][n][q]);
    }
  }
}

// ============ per-row 1/L2-norm of bf16 [NSUB,1024] ============
__global__ __launch_bounds__(256) void l2scale(const u16* __restrict__ H,
                                               float* __restrict__ rn) {
  const int lane = threadIdx.x & 63, wave = threadIdx.x >> 6;
  const int r = blockIdx.x * 4 + wave;
  const u16* row = H + (size_t)r * 1024 + lane * 16;
  int4 u0 = *(const int4*)row;
  int4 u1 = *(const int4*)(row + 8);
  float sq = 0.f;
  const int vals[8] = {u0.x, u0.y, u0.z, u0.w, u1.x, u1.y, u1.z, u1.w};
#pragma unroll
  for (int j = 0; j < 8; ++j) {
    u32 wv = (u32)vals[j];
    float f0 = __uint_as_float(wv << 16);
    float f1 = __uint_as_float(wv & 0xffff0000u);
    sq += f0 * f0 + f1 * f1;
  }
#pragma unroll
  for (int d = 1; d < 64; d <<= 1) sq += __shfl_xor(sq, d);
  if (lane == 0) rn[r] = 1.f / fmaxf(sqrtf(sq), 1e-12f);
}

extern "C" void kernel_launch(void* const* d_in, const int* in_sizes, int n_in,
                              void* d_out, int out_size, void* d_ws, size_t ws_size,
                              hipStream_t stream) {
  (void)in_sizes; (void)n_in; (void)out_size; (void)ws_size;
  const float* feat_full = (const float*)d_in[0];
  const int*   nodes = (const int*)d_in[1];
  const int*   arow = (const int*)d_in[2];
  const int*   acol = (const int*)d_in[3];
  const float* aval = (const float*)d_in[4];
  const float* W1_0 = (const float*)d_in[5];
  const float* W1_1 = (const float*)d_in[6];
  const float* b1_0 = (const float*)d_in[7];
  const float* b1_1 = (const float*)d_in[8];
  const float* s1_0 = (const float*)d_in[9];
  const float* s1_1 = (const float*)d_in[10];
  const float* o1_0 = (const float*)d_in[11];
  const float* o1_1 = (const float*)d_in[12];
  const float* W2_0 = (const float*)d_in[13];
  const float* W2_1 = (const float*)d_in[14];
  const float* b2_0 = (const float*)d_in[15];
  const float* b2_1 = (const float*)d_in[16];
  const float* s2_0 = (const float*)d_in[17];
  const float* s2_1 = (const float*)d_in[18];
  const float* o2_0 = (const float*)d_in[19];
  const float* o2_1 = (const float*)d_in[20];
  const float* Wc = (const float*)d_in[21];
  const float* bc = (const float*)d_in[22];
  float* out = (float*)d_out;

  const size_t MB = (size_t)1 << 20;
  char* p = (char*)d_ws;
  u16* FEAT = (u16*)p;                    // 32 MiB [NSUB,512]
  u16* S1   = (u16*)(p + 32 * MB);        // 32 MiB
  u16* H1   = (u16*)(p + 64 * MB);        // 64 MiB [NSUB,1024]
  u16* H2   = (u16*)(p + 128 * MB);       // 64 MiB
  u16* TMPa = (u16*)(p + 192 * MB);       // 32 MiB hop0 preact
  u16* TMPb = (u16*)(p + 224 * MB);       // 32 MiB hop1 preact
  u16* TTL  = (u16*)(p + 192 * MB);       // 64 MiB layer-2 preact (reuses TMPa/b)
  u16* W1_0b = (u16*)(p + 256 * MB);
  u16* W1_1b = W1_0b + 512 * 512;
  u16* W2cat = W1_1b + 512 * 512;         // [1024,1024]
  u16* Wcb   = W2cat + 1024 * 1024;
  int* row_off = (int*)(p + 260 * MB);
  int* cnt8    = (int*)(p + 261 * MB);
  int* cursor8 = (int*)(p + 262 * MB);
  float* RN    = (float*)(p + 263 * MB);
  int* bsum    = (int*)((char*)RN + 256 * 1024);
  int* boff    = bsum + 256;
  int2* cv     = (int2*)(p + 264 * MB);

  hipMemsetAsync(cnt8, 0, NSUB * 8 * sizeof(int), stream);

  // prep: gather ∥ edge-count ∥ weight casts
  u_prep<<<GATHER_B + COUNT_B + 2048, 256, 0, stream>>>(
      feat_full, nodes, FEAT, arow, acol, cnt8,
      W1_0, W1_1, W2_0, W2_1, Wc, W1_0b, W1_1b, W2cat, Wcb);

  scan_part<<<256, 256, 0, stream>>>(cnt8, bsum);
  scan_top<<<1, 256, 0, stream>>>(bsum, boff);
  scan_final<<<256, 256, 0, stream>>>(cnt8, boff, row_off, cursor8);
  edge_scatter8<<<NNZ_E / 256, 256, 0, stream>>>(arow, acol, aval, cursor8, cv);

  // ---- layer 1: union {gemm-hop0 ∥ spmm1}, then hop1 gemm + rownorms ----
  u_l1a<<<1024 + 8192, 256, 0, stream>>>(row_off, cv, FEAT, S1, W1_0b, TMPa);
  gemm_bt<512, 512, false, true, false><<<dim3(4, 256), 256, 0, stream>>>(
      S1, W1_1b, nullptr, nullptr, nullptr, TMPb);
  rownorm_k<<<NSUB / 4, 256, 0, stream>>>(TMPa, 512, b1_0, s1_0, o1_0, H1, 0);
  rownorm_k<<<NSUB / 4, 256, 0, stream>>>(TMPb, 512, b1_1, s1_1, o1_1, H1, 512);

  // ---- layer 2 (merged BK=64 GEMM -> TTL; union spmm2+norm ∥ rownorm2-hop0) ----
  gemm64_bt<1024, 1024><<<dim3(8, 256), 256, 0, stream>>>(H1, W2cat, TTL);
  u_l2<<<8192 + 8192, 256, 0, stream>>>(row_off, cv, TTL, H2,
                                        b2_0, s2_0, o2_0, b2_1, s2_1, o2_1);

  // ---- classifier with folded L2 normalization ----
  l2scale<<<NSUB / 4, 256, 0, stream>>>(H2, RN);
  gemm_bt<1024, 512, true, false, true><<<dim3(4, 256), 256, 0, stream>>>(
      H2, Wcb, bc, RN, out, nullptr);
}

// Round 14
// 625.557 us; speedup vs baseline: 1.4294x; 1.0127x over previous
//
#include <hip/hip_runtime.h>
#include <stdint.h>

typedef unsigned short u16;
typedef unsigned int u32;

#define NSUB 32768
#define NNZ_E 1048576

using short8 = __attribute__((ext_vector_type(8))) short;
using f32x4  = __attribute__((ext_vector_type(4))) float;

__device__ __forceinline__ u16 f2b(float f) {
  u32 u = __float_as_uint(f);
  return (u16)((u + 0x7fffu + ((u >> 16) & 1u)) >> 16);
}
__device__ __forceinline__ float b2f(u16 x) {
  return __uint_as_float(((u32)x) << 16);
}

__device__ __forceinline__ void glds16(const void* g, void* l) {
  __builtin_amdgcn_global_load_lds(
      (const __attribute__((address_space(1))) u32*)g,
      (__attribute__((address_space(3))) u32*)l, 16, 0, 0);
}

// ============ U_prep: gather ∥ edge-count ∥ 5x weight-cast ============
#define GATHER_B 16384
#define COUNT_B 4096
__global__ __launch_bounds__(256) void u_prep(
    const float* __restrict__ ff, const int* __restrict__ idx, u16* __restrict__ FEAT,
    const int* __restrict__ arow, const int* __restrict__ acol, int* __restrict__ cnt8,
    const float* W1_0, const float* W1_1, const float* W2_0, const float* W2_1,
    const float* Wc, u16* W1_0b, u16* W1_1b, u16* W2cat, u16* Wcb) {
  int bid = blockIdx.x, t = threadIdx.x;
  if (bid < GATHER_B) {
    int r = bid * 2 + (t >> 7);
    int c = (t & 127) * 4;
    size_t src = (size_t)idx[r];
    float4 v = *(const float4*)(ff + src * 512 + c);
    ushort4 o;
    o.x = f2b(v.x); o.y = f2b(v.y); o.z = f2b(v.z); o.w = f2b(v.w);
    *(ushort4*)(FEAT + (size_t)r * 512 + c) = o;
  } else if (bid < GATHER_B + COUNT_B) {
    int i = (bid - GATHER_B) * 256 + t;
    atomicAdd(&cnt8[arow[i] * 8 + (acol[i] >> 12)], 1);
  } else {
    int cid = bid - GATHER_B - COUNT_B;
    const float* src; u16* dst; int i;
    if (cid < 256)       { src = W1_0; dst = W1_0b;              i = cid * 256 + t; }
    else if (cid < 512)  { src = W1_1; dst = W1_1b;              i = (cid - 256) * 256 + t; }
    else if (cid < 1024) { src = W2_0; dst = W2cat;              i = (cid - 512) * 256 + t; }
    else if (cid < 1536) { src = W2_1; dst = W2cat + 512 * 1024; i = (cid - 1024) * 256 + t; }
    else                 { src = Wc;   dst = Wcb;                i = (cid - 1536) * 256 + t; }
    float4 v = ((const float4*)src)[i];
    ushort4 o;
    o.x = f2b(v.x); o.y = f2b(v.y); o.z = f2b(v.z); o.w = f2b(v.w);
    ((ushort4*)dst)[i] = o;
  }
}

// ============ hierarchical scan of cnt8[262144] ============
__global__ __launch_bounds__(256) void scan_part(const int* __restrict__ cnt8,
                                                 int* __restrict__ bsum) {
  int bid = blockIdx.x, t = threadIdx.x;
  int4 c = *(const int4*)(cnt8 + bid * 1024 + t * 4);
  int s = c.x + c.y + c.z + c.w;
#pragma unroll
  for (int d = 1; d < 64; d <<= 1) s += __shfl_xor(s, d);
  __shared__ int red[4];
  if ((t & 63) == 0) red[t >> 6] = s;
  __syncthreads();
  if (t == 0) bsum[bid] = red[0] + red[1] + red[2] + red[3];
}

__global__ __launch_bounds__(256) void scan_top(const int* __restrict__ bsum,
                                                int* __restrict__ boff) {
  int t = threadIdx.x;
  int v = bsum[t];
  int s = v;
#pragma unroll
  for (int d = 1; d < 64; d <<= 1) {
    int u = __shfl_up(s, d);
    if ((t & 63) >= d) s += u;
  }
  __shared__ int wsum[4];
  if ((t & 63) == 63) wsum[t >> 6] = s;
  __syncthreads();
  int add = 0;
  for (int w = 0; w < (t >> 6); ++w) add += wsum[w];
  boff[t] = s + add - v;  // exclusive
}

__global__ __launch_bounds__(256) void scan_final(const int* __restrict__ cnt8,
                                                  const int* __restrict__ boff,
                                                  int* __restrict__ off,
                                                  int* __restrict__ cursor8) {
  int bid = blockIdx.x, t = threadIdx.x;
  int base = bid * 1024 + t * 4;
  int4 c = *(const int4*)(cnt8 + base);
  int s = c.x + c.y + c.z + c.w;
  int inc = s;
#pragma unroll
  for (int d = 1; d < 64; d <<= 1) {
    int u = __shfl_up(inc, d);
    if ((t & 63) >= d) inc += u;
  }
  __shared__ int wsum[4];
  if ((t & 63) == 63) wsum[t >> 6] = inc;
  __syncthreads();
  int add = 0;
  for (int w = 0; w < (t >> 6); ++w) add += wsum[w];
  int run = boff[bid] + inc + add - s;
  int vals[4] = {c.x, c.y, c.z, c.w};
#pragma unroll
  for (int j = 0; j < 4; ++j) {
    int idx = base + j;
    cursor8[idx] = run;
    if ((idx & 7) == 0) off[idx >> 3] = run;
    run += vals[j];
  }
  if (bid == 255 && t == 255) off[NSUB] = run;
}

__global__ __launch_bounds__(256) void edge_scatter8(const int* __restrict__ row,
                                                     const int* __restrict__ col,
                                                     const float* __restrict__ val,
                                                     int* __restrict__ cursor8,
                                                     int2* __restrict__ cv) {
  int i = blockIdx.x * 256 + threadIdx.x;
  int c = col[i];
  int p = atomicAdd(&cursor8[row[i] * 8 + (c >> 12)], 1);
  int2 e; e.x = c; e.y = __float_as_int(val[i]);
  cv[p] = e;
}

// ============ shared epilogue: bias+relu+mean/var-norm of one 512-col row ============
__device__ __forceinline__ void norm_rowstore(float* a, int lane, int r,
                                              const float* __restrict__ bias,
                                              const float* __restrict__ sc,
                                              const float* __restrict__ ofs,
                                              u16* __restrict__ Y, int ldy, int col_off) {
  float4 b0 = *(const float4*)(bias + lane * 8);
  float4 b1 = *(const float4*)(bias + lane * 8 + 4);
  a[0] = fmaxf(a[0] + b0.x, 0.f); a[1] = fmaxf(a[1] + b0.y, 0.f);
  a[2] = fmaxf(a[2] + b0.z, 0.f); a[3] = fmaxf(a[3] + b0.w, 0.f);
  a[4] = fmaxf(a[4] + b1.x, 0.f); a[5] = fmaxf(a[5] + b1.y, 0.f);
  a[6] = fmaxf(a[6] + b1.z, 0.f); a[7] = fmaxf(a[7] + b1.w, 0.f);
  float sum = 0.f, sq = 0.f;
#pragma unroll
  for (int j = 0; j < 8; ++j) { sum += a[j]; sq += a[j] * a[j]; }
#pragma unroll
  for (int d = 1; d < 64; d <<= 1) {
    sum += __shfl_xor(sum, d);
    sq  += __shfl_xor(sq, d);
  }
  float mean = sum * (1.f / 512.f);
  float var = sq * (1.f / 512.f) - mean * mean;
  float rstd = rsqrtf(var + 1e-9f);
  float4 s0 = *(const float4*)(sc + lane * 8);
  float4 s1 = *(const float4*)(sc + lane * 8 + 4);
  float4 o0 = *(const float4*)(ofs + lane * 8);
  float4 o1 = *(const float4*)(ofs + lane * 8 + 4);
  int4 o;
  o.x = (int)((u32)f2b((a[0] - mean) * s0.x * rstd + o0.x) |
              ((u32)f2b((a[1] - mean) * s0.y * rstd + o0.y) << 16));
  o.y = (int)((u32)f2b((a[2] - mean) * s0.z * rstd + o0.z) |
              ((u32)f2b((a[3] - mean) * s0.w * rstd + o0.w) << 16));
  o.z = (int)((u32)f2b((a[4] - mean) * s1.x * rstd + o1.x) |
              ((u32)f2b((a[5] - mean) * s1.y * rstd + o1.y) << 16));
  o.w = (int)((u32)f2b((a[6] - mean) * s1.z * rstd + o1.z) |
              ((u32)f2b((a[7] - mean) * s1.w * rstd + o1.w) << 16));
  *(int4*)(Y + (size_t)r * ldy + col_off + lane * 8) = o;
}

// ============ SpMM, one wave per row, 16B gathers, MLP=4 ============
__device__ __forceinline__ void fma8(int4 u, float v, float* a) {
  u32 w;
  w = (u32)u.x; a[0] += v * __uint_as_float(w << 16); a[1] += v * __uint_as_float(w & 0xffff0000u);
  w = (u32)u.y; a[2] += v * __uint_as_float(w << 16); a[3] += v * __uint_as_float(w & 0xffff0000u);
  w = (u32)u.z; a[4] += v * __uint_as_float(w << 16); a[5] += v * __uint_as_float(w & 0xffff0000u);
  w = (u32)u.w; a[6] += v * __uint_as_float(w << 16); a[7] += v * __uint_as_float(w & 0xffff0000u);
}

template <int LDX, bool NORM>
__device__ __forceinline__ void spmm_dev(const int* __restrict__ off,
                                         const int2* __restrict__ cv,
                                         const u16* __restrict__ X,
                                         u16* __restrict__ Y, int ldy, int col_off,
                                         const float* __restrict__ bias,
                                         const float* __restrict__ sc,
                                         const float* __restrict__ ofs, int bid) {
  const int lane = threadIdx.x & 63, wave = threadIdx.x >> 6;
  const int r = bid * 4 + wave;
  const int s = __builtin_amdgcn_readfirstlane(off[r]);
  const int e = __builtin_amdgcn_readfirstlane(off[r + 1]);
  float a[8] = {0.f, 0.f, 0.f, 0.f, 0.f, 0.f, 0.f, 0.f};
  const u16* Xl = X + lane * 8;
  int i = s;
  for (; i + 4 <= e; i += 4) {
    int2 p0 = cv[i], p1 = cv[i + 1], p2 = cv[i + 2], p3 = cv[i + 3];
    int4 u0 = *(const int4*)(Xl + (size_t)p0.x * LDX);
    int4 u1 = *(const int4*)(Xl + (size_t)p1.x * LDX);
    int4 u2 = *(const int4*)(Xl + (size_t)p2.x * LDX);
    int4 u3 = *(const int4*)(Xl + (size_t)p3.x * LDX);
    fma8(u0, __int_as_float(p0.y), a);
    fma8(u1, __int_as_float(p1.y), a);
    fma8(u2, __int_as_float(p2.y), a);
    fma8(u3, __int_as_float(p3.y), a);
  }
  for (; i < e; ++i) {
    int2 p0 = cv[i];
    int4 u0 = *(const int4*)(Xl + (size_t)p0.x * LDX);
    fma8(u0, __int_as_float(p0.y), a);
  }
  if (NORM) {
    norm_rowstore(a, lane, r, bias, sc, ofs, Y, ldy, col_off);
  } else {
    int4 o;
    o.x = (int)((u32)f2b(a[0]) | ((u32)f2b(a[1]) << 16));
    o.y = (int)((u32)f2b(a[2]) | ((u32)f2b(a[3]) << 16));
    o.z = (int)((u32)f2b(a[4]) | ((u32)f2b(a[5]) << 16));
    o.w = (int)((u32)f2b(a[6]) | ((u32)f2b(a[7]) << 16));
    *(int4*)(Y + (size_t)r * ldy + col_off + lane * 8) = o;
  }
}

// ============ wave-per-row rownorm (bf16 in) ============
__device__ __forceinline__ void rownorm_dev(const u16* __restrict__ F, int ldf,
                                            const float* __restrict__ bias,
                                            const float* __restrict__ sc,
                                            const float* __restrict__ ofs,
                                            u16* __restrict__ Y, int ldy, int col_off,
                                            int bid) {
  const int lane = threadIdx.x & 63, wave = threadIdx.x >> 6;
  const int r = bid * 4 + wave;
  int4 u = *(const int4*)(F + (size_t)r * ldf + lane * 8);
  float a[8];
  a[0] = __uint_as_float(((u32)u.x) << 16); a[1] = __uint_as_float(((u32)u.x) & 0xffff0000u);
  a[2] = __uint_as_float(((u32)u.y) << 16); a[3] = __uint_as_float(((u32)u.y) & 0xffff0000u);
  a[4] = __uint_as_float(((u32)u.z) << 16); a[5] = __uint_as_float(((u32)u.z) & 0xffff0000u);
  a[6] = __uint_as_float(((u32)u.w) << 16); a[7] = __uint_as_float(((u32)u.w) & 0xffff0000u);
  norm_rowstore(a, lane, r, bias, sc, ofs, Y, ldy, col_off);
}

// ============ merged rownorm: TMPa -> H1[:, :512] ∥ TMPb -> H1[:, 512:] ============
__global__ __launch_bounds__(256) void rownorm2_k(const u16* __restrict__ TMPa,
                                                  const u16* __restrict__ TMPb,
                                                  const float* __restrict__ b1_0,
                                                  const float* __restrict__ s1_0,
                                                  const float* __restrict__ o1_0,
                                                  const float* __restrict__ b1_1,
                                                  const float* __restrict__ s1_1,
                                                  const float* __restrict__ o1_1,
                                                  u16* __restrict__ H1) {
  int bid = blockIdx.x;
  if (bid < 8192)
    rownorm_dev(TMPa, 512, b1_0, s1_0, o1_0, H1, 1024, 0, bid);
  else
    rownorm_dev(TMPb, 512, b1_1, s1_1, o1_1, H1, 1024, 512, bid - 8192);
}

// ============ U_l1a: spmm1 ∥ gemm1-hop0 (verbatim inline gemm, nwg=1024, gx=4) ============
__global__ __launch_bounds__(256) void u_l1a(const int* __restrict__ row_off,
                                             const int2* __restrict__ cv,
                                             const u16* __restrict__ FEAT,
                                             u16* __restrict__ S1,
                                             const u16* __restrict__ W1_0b,
                                             u16* __restrict__ TMPa) {
  if (blockIdx.x >= 1024) {
    spmm_dev<512, false>(row_off, cv, FEAT, S1, 512, 0, nullptr, nullptr, nullptr,
                         blockIdx.x - 1024);
    return;
  }
  __shared__ __align__(16) u16 As[128 * 32];
  __shared__ __align__(16) u16 Bs[128 * 32];
  const int K = 512, LDC = 512;
  const int t = threadIdx.x;
  const int lane = t & 63, wave = t >> 6;
  const int wm = (wave >> 1) * 64, wn = (wave & 1) * 64;
  const int nwg = 1024;
  const int bid = blockIdx.x;
  const int sbid = (bid % 8) * (nwg / 8) + bid / 8;
  const int bx = sbid % 4, by = sbid / 4;
  const int m0 = by * 128, n0 = bx * 128;

  f32x4 acc[4][4];
#pragma unroll
  for (int m = 0; m < 4; ++m)
#pragma unroll
    for (int n = 0; n < 4; ++n) acc[m][n] = f32x4{0.f, 0.f, 0.f, 0.f};

  const int lr = t >> 2;
  const int lc = (t & 3) * 8;
  const u16* Ag  = FEAT + (size_t)(m0 + lr) * K + lc;
  const u16* Ag2 = Ag + (size_t)64 * K;
  const u16* Wg  = W1_0b + (size_t)(n0 + lr) * K + lc;
  const u16* Wg2 = Wg + (size_t)64 * K;
  char* asb0 = (char*)As + wave * 1024;
  char* asb1 = (char*)As + 4096 + wave * 1024;
  char* bsb0 = (char*)Bs + wave * 1024;
  char* bsb1 = (char*)Bs + 4096 + wave * 1024;
  const int fr = lane & 15, kh = lane >> 4;

  for (int kt = 0; kt < K / 32; ++kt) {
    glds16(Ag + kt * 32, asb0);
    glds16(Ag2 + kt * 32, asb1);
    glds16(Wg + kt * 32, bsb0);
    glds16(Wg2 + kt * 32, bsb1);
    __syncthreads();
    short8 af[4], bfr[4];
#pragma unroll
    for (int m = 0; m < 4; ++m)
      af[m] = *(const short8*)&As[(wm + m * 16 + fr) * 32 + kh * 8];
#pragma unroll
    for (int n = 0; n < 4; ++n)
      bfr[n] = *(const short8*)&Bs[(wn + n * 16 + fr) * 32 + kh * 8];
#pragma unroll
    for (int m = 0; m < 4; ++m)
#pragma unroll
      for (int n = 0; n < 4; ++n)
        acc[m][n] = __builtin_amdgcn_mfma_f32_16x16x32_bf16(af[m], bfr[n], acc[m][n], 0, 0, 0);
    __syncthreads();
  }

  const int crow = (lane >> 4) * 4;  // C/D: row=(lane>>4)*4+reg, col=lane&15
  const int ccol = lane & 15;
#pragma unroll
  for (int n = 0; n < 4; ++n) {
    int col = n0 + wn + n * 16 + ccol;
#pragma unroll
    for (int m = 0; m < 4; ++m) {
      int row = m0 + wm + m * 16 + crow;
#pragma unroll
      for (int q = 0; q < 4; ++q)
        TMPa[(size_t)(row + q) * LDC + col] = f2b(acc[m][n][q]);
    }
  }
}

// ============ U_l2: spmm2(+norm) ∥ rownorm2-hop0 ============
__global__ __launch_bounds__(256) void u_l2(const int* __restrict__ row_off,
                                            const int2* __restrict__ cv,
                                            const u16* __restrict__ TTL,
                                            u16* __restrict__ H2,
                                            const float* __restrict__ b2_0,
                                            const float* __restrict__ s2_0,
                                            const float* __restrict__ o2_0,
                                            const float* __restrict__ b2_1,
                                            const float* __restrict__ s2_1,
                                            const float* __restrict__ o2_1) {
  int bid = blockIdx.x;
  if (bid < 8192)
    spmm_dev<1024, true>(row_off, cv, TTL + 512, H2, 1024, 512, b2_1, s2_1, o2_1, bid);
  else
    rownorm_dev(TTL, 1024, b2_0, s2_0, o2_0, H2, 1024, 0, bid - 8192);
}

// ============ bf16 MFMA GEMM, BK=64 + source-side XOR swizzle (all GEMMs) ============
// LDS rows are 128B (64 u16): slot s (16B) of row r stores global slot s^(r&7).
// Staged via glds16 with pre-swizzled per-lane GLOBAL address (LDS stays linear);
// reads apply the same XOR -> conflict-free ds_read_b128. HW-verified r13.
template <int K, int LDC, bool BIAS, bool BF16OUT, bool RS>
__global__ __launch_bounds__(256) void gemm64_bt(const u16* __restrict__ A,
                                                 const u16* __restrict__ W,
                                                 const float* __restrict__ bias,
                                                 const float* __restrict__ rs,
                                                 float* __restrict__ Cf,
                                                 u16* __restrict__ Cb) {
  __shared__ __align__(16) u16 As[128 * 64];
  __shared__ __align__(16) u16 Bs[128 * 64];
  const int t = threadIdx.x;
  const int lane = t & 63, wave = t >> 6;
  const int wm = (wave >> 1) * 64, wn = (wave & 1) * 64;
  const int nwg = gridDim.x * gridDim.y;
  const int bid = blockIdx.x + gridDim.x * blockIdx.y;
  const int sbid = (bid % 8) * (nwg / 8) + bid / 8;
  const int bx = sbid % gridDim.x, by = sbid / gridDim.x;
  const int m0 = by * 128, n0 = bx * 128;

  f32x4 acc[4][4];
#pragma unroll
  for (int m = 0; m < 4; ++m)
#pragma unroll
    for (int n = 0; n < 4; ++n) acc[m][n] = f32x4{0.f, 0.f, 0.f, 0.f};

  // staging: chunk c covers rows c*32..+32; thread t -> row c*32+(t>>3), LDS slot t&7;
  // global source slot = (t&7) ^ ((t>>3)&7)  [row&7 == (t>>3)&7]
  const int sr = t >> 3;
  const int ss = (t & 7) ^ (sr & 7);
  const u16* Asrc = A + (size_t)(m0 + sr) * K + ss * 8;
  const u16* Bsrc = W + (size_t)(n0 + sr) * K + ss * 8;
  char* adst = (char*)As + wave * 1024;
  char* bdst = (char*)Bs + wave * 1024;
  const int fr = lane & 15, kh = lane >> 4;
  const int sw = fr & 7;  // read-side XOR (row&7 == fr&7 since wm, m*16 are mult. of 8)

  for (int kt = 0; kt < K / 64; ++kt) {
#pragma unroll
    for (int c = 0; c < 4; ++c) {
      glds16(Asrc + (size_t)(c * 32) * K + kt * 64, adst + c * 4096);
      glds16(Bsrc + (size_t)(c * 32) * K + kt * 64, bdst + c * 4096);
    }
    __syncthreads();
#pragma unroll
    for (int kk = 0; kk < 2; ++kk) {
      const int so = ((kk * 4 + kh) ^ sw) * 8;
      short8 af[4], bfr[4];
#pragma unroll
      for (int m = 0; m < 4; ++m)
        af[m] = *(const short8*)&As[(wm + m * 16 + fr) * 64 + so];
#pragma unroll
      for (int n = 0; n < 4; ++n)
        bfr[n] = *(const short8*)&Bs[(wn + n * 16 + fr) * 64 + so];
#pragma unroll
      for (int m = 0; m < 4; ++m)
#pragma unroll
        for (int n = 0; n < 4; ++n)
          acc[m][n] = __builtin_amdgcn_mfma_f32_16x16x32_bf16(af[m], bfr[n], acc[m][n], 0, 0, 0);
    }
    __syncthreads();
  }

  const int crow = (lane >> 4) * 4;
  const int ccol = lane & 15;
#pragma unroll
  for (int n = 0; n < 4; ++n) {
    int col = n0 + wn + n * 16 + ccol;
    float bv = BIAS ? bias[col] : 0.f;
#pragma unroll
    for (int m = 0; m < 4; ++m) {
      int row = m0 + wm + m * 16 + crow;
#pragma unroll
      for (int q = 0; q < 4; ++q) {
        float v = acc[m][n][q];
        if (RS) v *= rs[row + q];
        v += bv;
        if (BF16OUT)
          Cb[(size_t)(row + q) * LDC + col] = f2b(v);
        else
          Cf[(size_t)(row + q) * LDC + col] = v;
      }
    }
  }
}

// ============ per-row 1/L2-norm of bf16 [NSUB,1024] ============
__global__ __launch_bounds__(256) void l2scale(const u16* __restrict__ H,
                                               float* __restrict__ rn) {
  const int lane = threadIdx.x & 63, wave = threadIdx.x >> 6;
  const int r = blockIdx.x * 4 + wave;
  const u16* row = H + (size_t)r * 1024 + lane * 16;
  int4 u0 = *(const int4*)row;
  int4 u1 = *(const int4*)(row + 8);
  float sq = 0.f;
  const int vals[8] = {u0.x, u0.y, u0.z, u0.w, u1.x, u1.y, u1.z, u1.w};
#pragma unroll
  for (int j = 0; j < 8; ++j) {
    u32 wv = (u32)vals[j];
    float f0 = __uint_as_float(wv << 16);
    float f1 = __uint_as_float(wv & 0xffff0000u);
    sq += f0 * f0 + f1 * f1;
  }
#pragma unroll
  for (int d = 1; d < 64; d <<= 1) sq += __shfl_xor(sq, d);
  if (lane == 0) rn[r] = 1.f / fmaxf(sqrtf(sq), 1e-12f);
}

extern "C" void kernel_launch(void* const* d_in, const int* in_sizes, int n_in,
                              void* d_out, int out_size, void* d_ws, size_t ws_size,
                              hipStream_t stream) {
  (void)in_sizes; (void)n_in; (void)out_size; (void)ws_size;
  const float* feat_full = (const float*)d_in[0];
  const int*   nodes = (const int*)d_in[1];
  const int*   arow = (const int*)d_in[2];
  const int*   acol = (const int*)d_in[3];
  const float* aval = (const float*)d_in[4];
  const float* W1_0 = (const float*)d_in[5];
  const float* W1_1 = (const float*)d_in[6];
  const float* b1_0 = (const float*)d_in[7];
  const float* b1_1 = (const float*)d_in[8];
  const float* s1_0 = (const float*)d_in[9];
  const float* s1_1 = (const float*)d_in[10];
  const float* o1_0 = (const float*)d_in[11];
  const float* o1_1 = (const float*)d_in[12];
  const float* W2_0 = (const float*)d_in[13];
  const float* W2_1 = (const float*)d_in[14];
  const float* b2_0 = (const float*)d_in[15];
  const float* b2_1 = (const float*)d_in[16];
  const float* s2_0 = (const float*)d_in[17];
  const float* s2_1 = (const float*)d_in[18];
  const float* o2_0 = (const float*)d_in[19];
  const float* o2_1 = (const float*)d_in[20];
  const float* Wc = (const float*)d_in[21];
  const float* bc = (const float*)d_in[22];
  float* out = (float*)d_out;

  const size_t MB = (size_t)1 << 20;
  char* p = (char*)d_ws;
  u16* FEAT = (u16*)p;                    // 32 MiB [NSUB,512]
  u16* S1   = (u16*)(p + 32 * MB);        // 32 MiB
  u16* H1   = (u16*)(p + 64 * MB);        // 64 MiB [NSUB,1024]
  u16* H2   = (u16*)(p + 128 * MB);       // 64 MiB
  u16* TMPa = (u16*)(p + 192 * MB);       // 32 MiB hop0 preact
  u16* TMPb = (u16*)(p + 224 * MB);       // 32 MiB hop1 preact
  u16* TTL  = (u16*)(p + 192 * MB);       // 64 MiB layer-2 preact (reuses TMPa/b)
  u16* W1_0b = (u16*)(p + 256 * MB);
  u16* W1_1b = W1_0b + 512 * 512;
  u16* W2cat = W1_1b + 512 * 512;         // [1024,1024]
  u16* Wcb   = W2cat + 1024 * 1024;
  int* row_off = (int*)(p + 260 * MB);
  int* cnt8    = (int*)(p + 261 * MB);
  int* cursor8 = (int*)(p + 262 * MB);
  float* RN    = (float*)(p + 263 * MB);
  int* bsum    = (int*)((char*)RN + 256 * 1024);
  int* boff    = bsum + 256;
  int2* cv     = (int2*)(p + 264 * MB);

  hipMemsetAsync(cnt8, 0, NSUB * 8 * sizeof(int), stream);

  // prep: gather ∥ edge-count ∥ weight casts
  u_prep<<<GATHER_B + COUNT_B + 2048, 256, 0, stream>>>(
      feat_full, nodes, FEAT, arow, acol, cnt8,
      W1_0, W1_1, W2_0, W2_1, Wc, W1_0b, W1_1b, W2cat, Wcb);

  scan_part<<<256, 256, 0, stream>>>(cnt8, bsum);
  scan_top<<<1, 256, 0, stream>>>(bsum, boff);
  scan_final<<<256, 256, 0, stream>>>(cnt8, boff, row_off, cursor8);
  edge_scatter8<<<NNZ_E / 256, 256, 0, stream>>>(arow, acol, aval, cursor8, cv);

  // ---- layer 1: union {gemm-hop0 ∥ spmm1}, then hop1 gemm64 + merged rownorm ----
  u_l1a<<<1024 + 8192, 256, 0, stream>>>(row_off, cv, FEAT, S1, W1_0b, TMPa);
  gemm64_bt<512, 512, false, true, false><<<dim3(4, 256), 256, 0, stream>>>(
      S1, W1_1b, nullptr, nullptr, nullptr, TMPb);
  rownorm2_k<<<16384, 256, 0, stream>>>(TMPa, TMPb, b1_0, s1_0, o1_0,
                                        b1_1, s1_1, o1_1, H1);

  // ---- layer 2 (merged BK=64 GEMM -> TTL; union spmm2+norm ∥ rownorm2-hop0) ----
  gemm64_bt<1024, 1024, false, true, false><<<dim3(8, 256), 256, 0, stream>>>(
      H1, W2cat, nullptr, nullptr, nullptr, TTL);
  u_l2<<<8192 + 8192, 256, 0, stream>>>(row_off, cv, TTL, H2,
                                        b2_0, s2_0, o2_0, b2_1, s2_1, o2_1);

  // ---- classifier with folded L2 normalization (gemm64 + bias + RS) ----
  l2scale<<<NSUB / 4, 256, 0, stream>>>(H2, RN);
  gemm64_bt<1024, 512, true, false, true><<<dim3(4, 256), 256, 0, stream>>>(
      H2, Wcb, bc, RN, out, nullptr);
}